// Round 15
// baseline (124.167 us; speedup 1.0000x reference)
//
#include <hip/hip_runtime.h>
#include <hip/hip_bf16.h>

#define N 1536
#define F 6
#define D 64
#define H 4
#define DH 16
#define FFDIM 256
#define NL 2
#define EPS 1e-5f
#define KS 16             // key splits across blocks
#define KB (N / KS)       // 96 keys per block
#define KW (KB / 4)       // 24 keys per wave
#define QB 256            // queries per block (4 per lane)
#define NPART KS          // partials per query after in-block combine

static __device__ __forceinline__ float dot4(float4 a, float4 b) {
    return a.x * b.x + a.y * b.y + a.z * b.z + a.w * b.w;
}

// ======== layer-0 fused proj+qkv+attention-partial ========
// proj and qkv are both linear, so compose: qkv_row(o) = nf @ eff[o] + beff[o].
union SmA {
    float sinw[48][D];                          // 12.3 KB (phase 2 only)
    struct { float k[KB][DH]; float v[KB][DH]; } kv;  // 12.3 KB (phases 3-4)
    float rd[2][QB][DH + 1];                    // 34.8 KB (phase 5)
};
__global__ __launch_bounds__(256) void k_attn0(const float* __restrict__ nf,
                                               const float* __restrict__ pw,
                                               const float* __restrict__ pb,
                                               const float* __restrict__ iw,
                                               const float* __restrict__ ib,
                                               float* __restrict__ x,
                                               float* __restrict__ accp,
                                               float* __restrict__ psump) {
    __shared__ __align__(16) SmA sm;
    __shared__ float pwl[D * F];
    __shared__ float pbl[D];
    __shared__ float nfk[KB * F];
    __shared__ float nfq[QB * F];
    __shared__ float eff[48][F];
    __shared__ float beff[48];
    int ks = blockIdx.x, qc = blockIdx.y, h = blockIdx.z;
    int t = threadIdx.x;
    int wv = t >> 6, lane = t & 63;

    // --- phase 1: stage proj weights, nf rows, and this head's in_w rows ---
    for (int i = t; i < D * F; i += 256) pwl[i] = pw[i];
    if (t < D) pbl[t] = pb[t];
    for (int i = t; i < KB * F; i += 256) nfk[i] = nf[ks * KB * F + i];
    for (int i = t; i < QB * F; i += 256) nfq[i] = nf[qc * QB * F + i];
    for (int i = t; i < 48 * D; i += 256) {
        int oo = i >> 6, e = i & 63;
        int o = (oo < 16) ? (h * DH + oo)
              : (oo < 32) ? (D + h * DH + (oo - 16))
                          : (2 * D + h * DH + (oo - 32));
        sm.sinw[oo][e] = iw[o * D + e];
    }
    __syncthreads();

    // --- phase 2: effective (composed) weights ---
    for (int i = t; i < 48 * F; i += 256) {
        int oo = i / F, fx = i % F;
        float a = 0.f;
#pragma unroll 8
        for (int e = 0; e < D; ++e) a += sm.sinw[oo][e] * pwl[e * F + fx];
        eff[oo][fx] = a;
    }
    if (t < 48) {
        int o = (t < 16) ? (h * DH + t)
              : (t < 32) ? (D + h * DH + (t - 16))
                         : (2 * D + h * DH + (t - 32));
        float a = ib[o];
#pragma unroll 8
        for (int e = 0; e < D; ++e) a += sm.sinw[t][e] * pbl[e];
        beff[t] = a;
    }
    __syncthreads();   // sinw dead; kv buffer may now be written

    // --- phase 3: K/V into LDS, q into regs, x write for designated blocks ---
    {
        int i = t & 31, rg = t >> 5;
        int oo = (i < 16) ? (16 + i) : (32 + (i - 16));
        float w0 = eff[oo][0], w1 = eff[oo][1], w2 = eff[oo][2];
        float w3 = eff[oo][3], w4 = eff[oo][4], w5 = eff[oo][5];
        float bo = beff[oo];
        for (int r = rg * (KB / 8); r < (rg + 1) * (KB / 8); ++r) {
            const float* nr = &nfk[r * F];
            float val = bo + nr[0] * w0 + nr[1] * w1 + nr[2] * w2
                           + nr[3] * w3 + nr[4] * w4 + nr[5] * w5;
            if (i < 16) sm.kv.k[r][i] = val;
            else        sm.kv.v[r][i - 16] = val;
        }
    }
    float q[4][DH];
#pragma unroll
    for (int j = 0; j < 4; ++j) {
        const float* nr = &nfq[(j * 64 + lane) * F];
        float n0 = nr[0], n1 = nr[1], n2 = nr[2], n3 = nr[3], n4 = nr[4], n5 = nr[5];
#pragma unroll
        for (int i = 0; i < DH; ++i)
            q[j][i] = 0.25f * (beff[i] + n0 * eff[i][0] + n1 * eff[i][1] + n2 * eff[i][2]
                                       + n3 * eff[i][3] + n4 * eff[i][4] + n5 * eff[i][5]);
    }
    if (ks == 0 && h == 0) {
        for (int i = t; i < QB * D; i += 256) {
            int row = i >> 6, e = i & 63;
            const float* nr = &nfq[row * F];
            float a = pbl[e];
#pragma unroll
            for (int f = 0; f < F; ++f) a += nr[f] * pwl[e * F + f];
            x[(qc * QB + row) * D + e] = a;
        }
    }
    __syncthreads();

    // --- phase 4: attention partial over this block's KB keys, 4 q/lane ---
    float acc[4][DH];
#pragma unroll
    for (int j = 0; j < 4; ++j)
#pragma unroll
        for (int i = 0; i < DH; ++i) acc[j][i] = 0.f;
    float psum[4] = {0.f, 0.f, 0.f, 0.f};

#pragma unroll 2
    for (int jk = 0; jk < KW; ++jk) {
        int r = wv * KW + jk;
        float4 k0 = *(const float4*)&sm.kv.k[r][0];
        float4 k1 = *(const float4*)&sm.kv.k[r][4];
        float4 k2 = *(const float4*)&sm.kv.k[r][8];
        float4 k3 = *(const float4*)&sm.kv.k[r][12];
        float p[4];
#pragma unroll
        for (int j = 0; j < 4; ++j) {
            float s = q[j][0] * k0.x + q[j][1] * k0.y + q[j][2] * k0.z + q[j][3] * k0.w
                    + q[j][4] * k1.x + q[j][5] * k1.y + q[j][6] * k1.z + q[j][7] * k1.w
                    + q[j][8] * k2.x + q[j][9] * k2.y + q[j][10] * k2.z + q[j][11] * k2.w
                    + q[j][12] * k3.x + q[j][13] * k3.y + q[j][14] * k3.z + q[j][15] * k3.w;
            p[j] = __expf(s);
            psum[j] += p[j];
        }
        float4 v0 = *(const float4*)&sm.kv.v[r][0];
        float4 v1 = *(const float4*)&sm.kv.v[r][4];
        float4 v2 = *(const float4*)&sm.kv.v[r][8];
        float4 v3 = *(const float4*)&sm.kv.v[r][12];
#pragma unroll
        for (int j = 0; j < 4; ++j) {
            acc[j][0] += p[j] * v0.x;  acc[j][1] += p[j] * v0.y;
            acc[j][2] += p[j] * v0.z;  acc[j][3] += p[j] * v0.w;
            acc[j][4] += p[j] * v1.x;  acc[j][5] += p[j] * v1.y;
            acc[j][6] += p[j] * v1.z;  acc[j][7] += p[j] * v1.w;
            acc[j][8] += p[j] * v2.x;  acc[j][9] += p[j] * v2.y;
            acc[j][10] += p[j] * v2.z; acc[j][11] += p[j] * v2.w;
            acc[j][12] += p[j] * v3.x; acc[j][13] += p[j] * v3.y;
            acc[j][14] += p[j] * v3.z; acc[j][15] += p[j] * v3.w;
        }
    }

    __syncthreads();  // all kv reads done before rd overlay is written
    // 2-step combine: waves 0,1 write rd[0],rd[1]; waves 2,3 accumulate in.
    if (wv < 2) {
#pragma unroll
        for (int j = 0; j < 4; ++j) {
            int qq = j * 64 + lane;
#pragma unroll
            for (int i = 0; i < DH; ++i) sm.rd[wv][qq][i] = acc[j][i];
            sm.rd[wv][qq][DH] = psum[j];
        }
    }
    __syncthreads();
    if (wv >= 2) {
        int w2 = wv - 2;
#pragma unroll
        for (int j = 0; j < 4; ++j) {
            int qq = j * 64 + lane;
#pragma unroll
            for (int i = 0; i < DH; ++i) sm.rd[w2][qq][i] += acc[j][i];
            sm.rd[w2][qq][DH] += psum[j];
        }
    }
    __syncthreads();

    for (int i = t; i < QB * (DH + 1); i += 256) {
        int qq = i / (DH + 1), c = i % (DH + 1);
        float s = sm.rd[0][qq][c] + sm.rd[1][qq][c];
        int n = qc * QB + qq;
        if (c < DH)
            accp[((size_t)ks * N + n) * D + h * DH + c] = s;
        else
            psump[((size_t)ks * N + n) * H + h] = s;
    }
}

// ======== layer-1 attention partial (reads qkv buffer) ========
struct SmemKV { float k[KB][DH]; float v[KB][DH]; };
__global__ __launch_bounds__(256) void k_attn_part(const float* __restrict__ qkv,
                                                   float* __restrict__ accp,
                                                   float* __restrict__ psump) {
    __shared__ __align__(16) union {
        SmemKV kv;
        float rd[2][QB][DH + 1];
    } sm;
    int ks = blockIdx.x, qc = blockIdx.y, h = blockIdx.z;
    int t = threadIdx.x;
    int wv = t >> 6, lane = t & 63;

    for (int i = t; i < KB * 4; i += 256) {
        int row = i >> 2, c4 = (i & 3) * 4;
        const float* base = qkv + (size_t)(ks * KB + row) * (3 * D) + D + h * DH + c4;
        *(float4*)&sm.kv.k[row][c4] = *(const float4*)base;
        *(float4*)&sm.kv.v[row][c4] = *(const float4*)(base + D);
    }

    float q[4][DH];
#pragma unroll
    for (int j = 0; j < 4; ++j) {
        const float4* qp =
            (const float4*)(qkv + (size_t)(qc * QB + j * 64 + lane) * (3 * D) + h * DH);
#pragma unroll
        for (int e = 0; e < 4; ++e) {
            float4 v = qp[e];
            q[j][e * 4 + 0] = v.x * 0.25f;
            q[j][e * 4 + 1] = v.y * 0.25f;
            q[j][e * 4 + 2] = v.z * 0.25f;
            q[j][e * 4 + 3] = v.w * 0.25f;
        }
    }
    __syncthreads();

    float acc[4][DH];
#pragma unroll
    for (int j = 0; j < 4; ++j)
#pragma unroll
        for (int i = 0; i < DH; ++i) acc[j][i] = 0.f;
    float psum[4] = {0.f, 0.f, 0.f, 0.f};

#pragma unroll 2
    for (int jk = 0; jk < KW; ++jk) {
        int r = wv * KW + jk;
        float4 k0 = *(const float4*)&sm.kv.k[r][0];
        float4 k1 = *(const float4*)&sm.kv.k[r][4];
        float4 k2 = *(const float4*)&sm.kv.k[r][8];
        float4 k3 = *(const float4*)&sm.kv.k[r][12];
        float p[4];
#pragma unroll
        for (int j = 0; j < 4; ++j) {
            float s = q[j][0] * k0.x + q[j][1] * k0.y + q[j][2] * k0.z + q[j][3] * k0.w
                    + q[j][4] * k1.x + q[j][5] * k1.y + q[j][6] * k1.z + q[j][7] * k1.w
                    + q[j][8] * k2.x + q[j][9] * k2.y + q[j][10] * k2.z + q[j][11] * k2.w
                    + q[j][12] * k3.x + q[j][13] * k3.y + q[j][14] * k3.z + q[j][15] * k3.w;
            p[j] = __expf(s);
            psum[j] += p[j];
        }
        float4 v0 = *(const float4*)&sm.kv.v[r][0];
        float4 v1 = *(const float4*)&sm.kv.v[r][4];
        float4 v2 = *(const float4*)&sm.kv.v[r][8];
        float4 v3 = *(const float4*)&sm.kv.v[r][12];
#pragma unroll
        for (int j = 0; j < 4; ++j) {
            acc[j][0] += p[j] * v0.x;  acc[j][1] += p[j] * v0.y;
            acc[j][2] += p[j] * v0.z;  acc[j][3] += p[j] * v0.w;
            acc[j][4] += p[j] * v1.x;  acc[j][5] += p[j] * v1.y;
            acc[j][6] += p[j] * v1.z;  acc[j][7] += p[j] * v1.w;
            acc[j][8] += p[j] * v2.x;  acc[j][9] += p[j] * v2.y;
            acc[j][10] += p[j] * v2.z; acc[j][11] += p[j] * v2.w;
            acc[j][12] += p[j] * v3.x; acc[j][13] += p[j] * v3.y;
            acc[j][14] += p[j] * v3.z; acc[j][15] += p[j] * v3.w;
        }
    }

    __syncthreads();
    if (wv < 2) {
#pragma unroll
        for (int j = 0; j < 4; ++j) {
            int qq = j * 64 + lane;
#pragma unroll
            for (int i = 0; i < DH; ++i) sm.rd[wv][qq][i] = acc[j][i];
            sm.rd[wv][qq][DH] = psum[j];
        }
    }
    __syncthreads();
    if (wv >= 2) {
        int w2 = wv - 2;
#pragma unroll
        for (int j = 0; j < 4; ++j) {
            int qq = j * 64 + lane;
#pragma unroll
            for (int i = 0; i < DH; ++i) sm.rd[w2][qq][i] += acc[j][i];
            sm.rd[w2][qq][DH] += psum[j];
        }
    }
    __syncthreads();

    for (int i = t; i < QB * (DH + 1); i += 256) {
        int qq = i / (DH + 1), c = i % (DH + 1);
        float s = sm.rd[0][qq][c] + sm.rd[1][qq][c];
        int n = qc * QB + qq;
        if (c < DH)
            accp[((size_t)ks * N + n) * D + h * DH + c] = s;
        else
            psump[((size_t)ks * N + n) * H + h] = s;
    }
}

// --- fused: combine partials -> o; out-proj+LN1; ff1; ff2; LN2;
//     optional tail A: qkv for next layer; optional tail B: node+uw. ---
__global__ __launch_bounds__(256) void k_attn_ffn(const float* __restrict__ accp,
                                                  const float* __restrict__ psump,
                                                  const float* __restrict__ ow,
                                                  const float* __restrict__ ob,
                                                  const float* __restrict__ g1,
                                                  const float* __restrict__ be1,
                                                  const float* __restrict__ w1,
                                                  const float* __restrict__ b1,
                                                  const float* __restrict__ w2,
                                                  const float* __restrict__ b2,
                                                  const float* __restrict__ g2,
                                                  const float* __restrict__ be2,
                                                  float* __restrict__ x,
                                                  const float* __restrict__ nw,
                                                  const float* __restrict__ nb,
                                                  float* __restrict__ nqkv,
                                                  int tail,
                                                  const float* __restrict__ nsw,
                                                  const float* __restrict__ nsb,
                                                  const float* __restrict__ e1w,
                                                  const float* __restrict__ e1b,
                                                  float* __restrict__ nodeo,
                                                  float* __restrict__ u,
                                                  float* __restrict__ wbuf) {
    __shared__ __align__(16) float so[4][D];
    __shared__ __align__(16) float sx[4][D];
    __shared__ __align__(16) float sh[4][FFDIM];
    __shared__ float sp[4][4][D];
    int t = threadIdx.x;
    int r = t >> 6, e = t & 63;
    int n = blockIdx.x * 4 + r;

    {
        float a = 0.f, p = 0.f;
#pragma unroll 8
        for (int pp = 0; pp < NPART; ++pp) {
            a += accp[((size_t)pp * N + n) * D + e];
            p += psump[((size_t)pp * N + n) * H + (e >> 4)];
        }
        so[r][e] = a / p;
    }
    __syncthreads();

    {
        const float4* ir = (const float4*)so[r];
        const float4* wr = (const float4*)(ow + e * D);
        float acc = ob[e];
#pragma unroll
        for (int k = 0; k < D / 4; ++k) acc += dot4(ir[k], wr[k]);
        float y = x[n * D + e] + acc;
        float mu = y;
#pragma unroll
        for (int off = 32; off; off >>= 1) mu += __shfl_xor(mu, off, 64);
        mu *= (1.f / 64.f);
        float diff = y - mu;
        float var = diff * diff;
#pragma unroll
        for (int off = 32; off; off >>= 1) var += __shfl_xor(var, off, 64);
        var *= (1.f / 64.f);
        sx[r][e] = diff * rsqrtf(var + EPS) * g1[e] + be1[e];
    }
    __syncthreads();

    {
        const float4* wr = (const float4*)(w1 + t * D);
        float acc[4];
        float bb = b1[t];
#pragma unroll
        for (int rr = 0; rr < 4; ++rr) acc[rr] = bb;
#pragma unroll
        for (int k = 0; k < D / 4; ++k) {
            float4 wv = wr[k];
#pragma unroll
            for (int rr = 0; rr < 4; ++rr) acc[rr] += dot4(wv, *(const float4*)&sx[rr][k * 4]);
        }
#pragma unroll
        for (int rr = 0; rr < 4; ++rr) sh[rr][t] = fmaxf(acc[rr], 0.f);
    }
    __syncthreads();

    {
        int d = t & 63, c = t >> 6;
        const float4* wr = (const float4*)(w2 + d * FFDIM + c * 64);
        float acc[4] = {0.f, 0.f, 0.f, 0.f};
#pragma unroll
        for (int k = 0; k < 16; ++k) {
            float4 wv = wr[k];
#pragma unroll
            for (int rr = 0; rr < 4; ++rr)
                acc[rr] += dot4(wv, *(const float4*)&sh[rr][c * 64 + k * 4]);
        }
#pragma unroll
        for (int rr = 0; rr < 4; ++rr) sp[rr][c][d] = acc[rr];
    }
    __syncthreads();

    {
        float y = sx[r][e] + b2[e] + sp[r][0][e] + sp[r][1][e] + sp[r][2][e] + sp[r][3][e];
        float mu = y;
#pragma unroll
        for (int off = 32; off; off >>= 1) mu += __shfl_xor(mu, off, 64);
        mu *= (1.f / 64.f);
        float diff = y - mu;
        float var = diff * diff;
#pragma unroll
        for (int off = 32; off; off >>= 1) var += __shfl_xor(var, off, 64);
        var *= (1.f / 64.f);
        float xv = diff * rsqrtf(var + EPS) * g2[e] + be2[e];
        x[n * D + e] = xv;
        sx[r][e] = xv;
    }

    if (nqkv) {
        __syncthreads();
        if (t < 3 * D) {
            const float4* wr = (const float4*)(nw + t * D);
            float bb = nb[t];
            float a0 = bb, a1 = bb, a2 = bb, a3 = bb;
#pragma unroll
            for (int k = 0; k < D / 4; ++k) {
                float4 wv = wr[k];
                a0 += dot4(wv, *(const float4*)&sx[0][k * 4]);
                a1 += dot4(wv, *(const float4*)&sx[1][k * 4]);
                a2 += dot4(wv, *(const float4*)&sx[2][k * 4]);
                a3 += dot4(wv, *(const float4*)&sx[3][k * 4]);
            }
            int n0 = blockIdx.x * 4;
            nqkv[(n0 + 0) * (3 * D) + t] = a0;
            nqkv[(n0 + 1) * (3 * D) + t] = a1;
            nqkv[(n0 + 2) * (3 * D) + t] = a2;
            nqkv[(n0 + 3) * (3 * D) + t] = a3;
        }
    }

    if (!tail) return;
    __syncthreads();

    {
        const float4* xr = (const float4*)sx[r];
        const float4* ar = (const float4*)(e1w + e * 2 * D);
        const float4* br = (const float4*)(e1w + e * 2 * D + D);
        float au = 0.f, aw = 0.f;
#pragma unroll
        for (int k = 0; k < D / 4; ++k) {
            float4 xv = xr[k], av = ar[k], bv = br[k];
            au += dot4(xv, av);
            aw += dot4(xv, bv);
        }
        u[n * D + e] = au + e1b[e];
        wbuf[n * D + e] = aw;
        float p = sx[r][e] * nsw[e];
#pragma unroll
        for (int off = 32; off; off >>= 1) p += __shfl_xor(p, off, 64);
        if (e == 0) nodeo[n] = p + nsb[0];
    }
}

// -------- edge: 64x64 tile/block, 4x4 register blocking, float4 LDS --------
__global__ __launch_bounds__(256) void k_edge(const float* __restrict__ u,
                                              const float* __restrict__ w,
                                              const float* __restrict__ e2w,
                                              const float* __restrict__ e2b,
                                              float* __restrict__ out) {
    __shared__ __align__(16) float su[64][68];
    __shared__ __align__(16) float sw[64][68];
    __shared__ __align__(16) float sv[64];
    int tn = blockIdx.y * 64, tm = blockIdx.x * 64;
    int t = threadIdx.x;
    for (int i = t; i < 64 * 16; i += 256) {
        int r = i >> 4, c4 = (i & 15) * 4;
        *(float4*)&su[r][c4] = *(const float4*)&u[(tn + r) * D + c4];
        *(float4*)&sw[r][c4] = *(const float4*)&w[(tm + r) * D + c4];
    }
    if (t < 64) sv[t] = e2w[t];
    __syncthreads();
    float eb = e2b[0];
    int c0 = t & 15, r0 = t >> 4;

    float acc[4][4];
#pragma unroll
    for (int j = 0; j < 4; ++j)
#pragma unroll
        for (int k = 0; k < 4; ++k) acc[j][k] = 0.f;

#pragma unroll 4
    for (int e0 = 0; e0 < 64; e0 += 4) {
        float4 vv = *(const float4*)&sv[e0];
        float4 a[4], bb[4];
#pragma unroll
        for (int j = 0; j < 4; ++j) a[j] = *(const float4*)&su[r0 + 16 * j][e0];
#pragma unroll
        for (int k = 0; k < 4; ++k) bb[k] = *(const float4*)&sw[c0 + 16 * k][e0];
#pragma unroll
        for (int j = 0; j < 4; ++j)
#pragma unroll
            for (int k = 0; k < 4; ++k) {
                acc[j][k] += fmaxf(a[j].x + bb[k].x, 0.f) * vv.x;
                acc[j][k] += fmaxf(a[j].y + bb[k].y, 0.f) * vv.y;
                acc[j][k] += fmaxf(a[j].z + bb[k].z, 0.f) * vv.z;
                acc[j][k] += fmaxf(a[j].w + bb[k].w, 0.f) * vv.w;
            }
    }
#pragma unroll
    for (int j = 0; j < 4; ++j)
#pragma unroll
        for (int k = 0; k < 4; ++k)
            out[(size_t)(tn + r0 + 16 * j) * N + (tm + c0 + 16 * k)] = acc[j][k] + eb;
}

extern "C" void kernel_launch(void* const* d_in, const int* in_sizes, int n_in,
                              void* d_out, int out_size, void* d_ws, size_t ws_size,
                              hipStream_t stream) {
    const float* node_feats = (const float*)d_in[0];
    const float* proj_w = (const float*)d_in[1];
    const float* proj_b = (const float*)d_in[2];
    const float* in_w = (const float*)d_in[3];
    const float* in_b = (const float*)d_in[4];
    const float* out_w = (const float*)d_in[5];
    const float* out_b = (const float*)d_in[6];
    const float* ff1_w = (const float*)d_in[7];
    const float* ff1_b = (const float*)d_in[8];
    const float* ff2_w = (const float*)d_in[9];
    const float* ff2_b = (const float*)d_in[10];
    const float* ln1_g = (const float*)d_in[11];
    const float* ln1_b = (const float*)d_in[12];
    const float* ln2_g = (const float*)d_in[13];
    const float* ln2_b = (const float*)d_in[14];
    const float* ns_w = (const float*)d_in[15];
    const float* ns_b = (const float*)d_in[16];
    const float* e1_w = (const float*)d_in[17];
    const float* e1_b = (const float*)d_in[18];
    const float* e2_w = (const float*)d_in[19];
    const float* e2_b = (const float*)d_in[20];

    float* out = (float*)d_out;  // [0,1536) node logits, then 1536^2 edge logits

    float* x = (float*)d_ws;               // N*D
    float* qkv = x + N * D;                // N*3D (layer 1 only)
    float* accp = qkv + N * 3 * D;         // NPART*N*D (6.3 MB)
    float* psump = accp + (size_t)NPART * N * D;  // NPART*N*H
    float* u = psump + (size_t)NPART * N * H;     // N*D
    float* wbuf = u + N * D;               // N*D

    dim3 agrid(KS, N / QB, H);

    // layer 0: fused proj+qkv+attention (x written by ks==0,h==0 blocks)
    k_attn0<<<agrid, 256, 0, stream>>>(node_feats, proj_w, proj_b,
                                       in_w, in_b, x, accp, psump);
    // layer 0 epilogue + layer-1 qkv production
    k_attn_ffn<<<N / 4, 256, 0, stream>>>(
        accp, psump, out_w, out_b, ln1_g, ln1_b,
        ff1_w, ff1_b, ff2_w, ff2_b, ln2_g, ln2_b, x,
        in_w + (size_t)3 * D * D, in_b + 3 * D, qkv,
        0, nullptr, nullptr, nullptr, nullptr, nullptr, nullptr, nullptr);
    // layer 1 attention
    k_attn_part<<<agrid, 256, 0, stream>>>(qkv, accp, psump);
    // layer 1 epilogue + node/uw tail
    k_attn_ffn<<<N / 4, 256, 0, stream>>>(
        accp, psump, out_w + (size_t)D * D, out_b + D,
        ln1_g + D, ln1_b + D,
        ff1_w + (size_t)FFDIM * D, ff1_b + FFDIM,
        ff2_w + (size_t)D * FFDIM, ff2_b + D,
        ln2_g + D, ln2_b + D, x,
        nullptr, nullptr, nullptr,
        1, ns_w, ns_b, e1_w, e1_b, out, u, wbuf);
    // edge head
    {
        dim3 grid(N / 64, N / 64);
        k_edge<<<grid, 256, 0, stream>>>(u, wbuf, e2_w, e2_b, out + N);
    }
}

// Round 16
// 108.641 us; speedup vs baseline: 1.1429x; 1.1429x over previous
//
#include <hip/hip_runtime.h>
#include <hip/hip_bf16.h>

#define N 1536
#define F 6
#define D 64
#define H 4
#define DH 16
#define FFDIM 256
#define NL 2
#define EPS 1e-5f
#define KS 8              // key splits across blocks
#define KB (N / KS)       // 192 keys per block
#define NW 8              // waves per attention block (512 threads)
#define KW (KB / NW)      // 24 keys per wave
#define QB 128            // queries per block (2 per lane)
#define NPART KS          // partials per query after in-block combine

static __device__ __forceinline__ float dot4(float4 a, float4 b) {
    return a.x * b.x + a.y * b.y + a.z * b.z + a.w * b.w;
}

// ======== layer-0 fused proj+qkv+attention-partial (512 threads) ========
// proj and qkv are both linear, so compose: qkv_row(o) = nf @ eff[o] + beff[o].
union SmA {
    float sinw[48][D];                          // 12.3 KB (phase 2 only)
    struct { float k[KB][DH]; float v[KB][DH]; } kv;  // 24.6 KB (phases 3-4)
    float rd[4][QB][DH + 1];                    // 34.8 KB (phase 5, 2-step)
};
__global__ __launch_bounds__(512) void k_attn0(const float* __restrict__ nf,
                                               const float* __restrict__ pw,
                                               const float* __restrict__ pb,
                                               const float* __restrict__ iw,
                                               const float* __restrict__ ib,
                                               float* __restrict__ x,
                                               float* __restrict__ accp,
                                               float* __restrict__ psump) {
    __shared__ __align__(16) SmA sm;
    __shared__ float pwl[D * F];
    __shared__ float pbl[D];
    __shared__ float nfk[KB * F];
    __shared__ float nfq[QB * F];
    __shared__ float eff[48][F];
    __shared__ float beff[48];
    int ks = blockIdx.x, qc = blockIdx.y, h = blockIdx.z;
    int t = threadIdx.x;
    int wv = t >> 6, lane = t & 63;

    // --- phase 1: stage proj weights, nf rows, and this head's in_w rows ---
    for (int i = t; i < D * F; i += 512) pwl[i] = pw[i];
    if (t < D) pbl[t] = pb[t];
    for (int i = t; i < KB * F; i += 512) nfk[i] = nf[ks * KB * F + i];
    for (int i = t; i < QB * F; i += 512) nfq[i] = nf[qc * QB * F + i];
    for (int i = t; i < 48 * D; i += 512) {
        int oo = i >> 6, e = i & 63;
        int o = (oo < 16) ? (h * DH + oo)
              : (oo < 32) ? (D + h * DH + (oo - 16))
                          : (2 * D + h * DH + (oo - 32));
        sm.sinw[oo][e] = iw[o * D + e];
    }
    __syncthreads();

    // --- phase 2: effective (composed) weights ---
    for (int i = t; i < 48 * F; i += 512) {
        int oo = i / F, fx = i % F;
        float a = 0.f;
#pragma unroll 8
        for (int e = 0; e < D; ++e) a += sm.sinw[oo][e] * pwl[e * F + fx];
        eff[oo][fx] = a;
    }
    if (t < 48) {
        int o = (t < 16) ? (h * DH + t)
              : (t < 32) ? (D + h * DH + (t - 16))
                         : (2 * D + h * DH + (t - 32));
        float a = ib[o];
#pragma unroll 8
        for (int e = 0; e < D; ++e) a += sm.sinw[t][e] * pbl[e];
        beff[t] = a;
    }
    __syncthreads();   // sinw dead; kv buffer may now be written

    // --- phase 3: K/V into LDS, q into regs, x write for designated blocks ---
    {
        int i = t & 31, rg = t >> 5;   // rg in [0,16): 12 rows each
        int oo = (i < 16) ? (16 + i) : (32 + (i - 16));
        float w0 = eff[oo][0], w1 = eff[oo][1], w2 = eff[oo][2];
        float w3 = eff[oo][3], w4 = eff[oo][4], w5 = eff[oo][5];
        float bo = beff[oo];
        for (int r = rg * (KB / 16); r < (rg + 1) * (KB / 16); ++r) {
            const float* nr = &nfk[r * F];
            float val = bo + nr[0] * w0 + nr[1] * w1 + nr[2] * w2
                           + nr[3] * w3 + nr[4] * w4 + nr[5] * w5;
            if (i < 16) sm.kv.k[r][i] = val;
            else        sm.kv.v[r][i - 16] = val;
        }
    }
    float q[2][DH];
#pragma unroll
    for (int j = 0; j < 2; ++j) {
        const float* nr = &nfq[(j * 64 + lane) * F];
        float n0 = nr[0], n1 = nr[1], n2 = nr[2], n3 = nr[3], n4 = nr[4], n5 = nr[5];
#pragma unroll
        for (int i = 0; i < DH; ++i)
            q[j][i] = 0.25f * (beff[i] + n0 * eff[i][0] + n1 * eff[i][1] + n2 * eff[i][2]
                                       + n3 * eff[i][3] + n4 * eff[i][4] + n5 * eff[i][5]);
    }
    if (ks == 0 && h == 0) {
        for (int i = t; i < QB * D; i += 512) {
            int row = i >> 6, e = i & 63;
            const float* nr = &nfq[row * F];
            float a = pbl[e];
#pragma unroll
            for (int f = 0; f < F; ++f) a += nr[f] * pwl[e * F + f];
            x[(qc * QB + row) * D + e] = a;
        }
    }
    __syncthreads();

    // --- phase 4: attention partial over this wave's KW keys, 2 q/lane ---
    float acc[2][DH];
#pragma unroll
    for (int j = 0; j < 2; ++j)
#pragma unroll
        for (int i = 0; i < DH; ++i) acc[j][i] = 0.f;
    float psum[2] = {0.f, 0.f};

#pragma unroll 2
    for (int jk = 0; jk < KW; ++jk) {
        int r = wv * KW + jk;
        float4 k0 = *(const float4*)&sm.kv.k[r][0];
        float4 k1 = *(const float4*)&sm.kv.k[r][4];
        float4 k2 = *(const float4*)&sm.kv.k[r][8];
        float4 k3 = *(const float4*)&sm.kv.k[r][12];
        float p[2];
#pragma unroll
        for (int j = 0; j < 2; ++j) {
            float s = q[j][0] * k0.x + q[j][1] * k0.y + q[j][2] * k0.z + q[j][3] * k0.w
                    + q[j][4] * k1.x + q[j][5] * k1.y + q[j][6] * k1.z + q[j][7] * k1.w
                    + q[j][8] * k2.x + q[j][9] * k2.y + q[j][10] * k2.z + q[j][11] * k2.w
                    + q[j][12] * k3.x + q[j][13] * k3.y + q[j][14] * k3.z + q[j][15] * k3.w;
            p[j] = __expf(s);
            psum[j] += p[j];
        }
        float4 v0 = *(const float4*)&sm.kv.v[r][0];
        float4 v1 = *(const float4*)&sm.kv.v[r][4];
        float4 v2 = *(const float4*)&sm.kv.v[r][8];
        float4 v3 = *(const float4*)&sm.kv.v[r][12];
#pragma unroll
        for (int j = 0; j < 2; ++j) {
            acc[j][0] += p[j] * v0.x;  acc[j][1] += p[j] * v0.y;
            acc[j][2] += p[j] * v0.z;  acc[j][3] += p[j] * v0.w;
            acc[j][4] += p[j] * v1.x;  acc[j][5] += p[j] * v1.y;
            acc[j][6] += p[j] * v1.z;  acc[j][7] += p[j] * v1.w;
            acc[j][8] += p[j] * v2.x;  acc[j][9] += p[j] * v2.y;
            acc[j][10] += p[j] * v2.z; acc[j][11] += p[j] * v2.w;
            acc[j][12] += p[j] * v3.x; acc[j][13] += p[j] * v3.y;
            acc[j][14] += p[j] * v3.z; acc[j][15] += p[j] * v3.w;
        }
    }

    __syncthreads();  // all kv reads done before rd overlay is written
    // 2-step combine: waves 0-3 write rd[wv]; waves 4-7 accumulate in.
    if (wv < 4) {
#pragma unroll
        for (int j = 0; j < 2; ++j) {
            int qq = j * 64 + lane;
#pragma unroll
            for (int i = 0; i < DH; ++i) sm.rd[wv][qq][i] = acc[j][i];
            sm.rd[wv][qq][DH] = psum[j];
        }
    }
    __syncthreads();
    if (wv >= 4) {
        int w2 = wv - 4;
#pragma unroll
        for (int j = 0; j < 2; ++j) {
            int qq = j * 64 + lane;
#pragma unroll
            for (int i = 0; i < DH; ++i) sm.rd[w2][qq][i] += acc[j][i];
            sm.rd[w2][qq][DH] += psum[j];
        }
    }
    __syncthreads();

    for (int i = t; i < QB * (DH + 1); i += 512) {
        int qq = i / (DH + 1), c = i % (DH + 1);
        float s = sm.rd[0][qq][c] + sm.rd[1][qq][c] + sm.rd[2][qq][c] + sm.rd[3][qq][c];
        int n = qc * QB + qq;
        if (c < DH)
            accp[((size_t)ks * N + n) * D + h * DH + c] = s;
        else
            psump[((size_t)ks * N + n) * H + h] = s;
    }
}

// ======== layer-1 attention partial (512 threads, reads qkv buffer) ========
struct SmemKV { float k[KB][DH]; float v[KB][DH]; };
__global__ __launch_bounds__(512) void k_attn_part(const float* __restrict__ qkv,
                                                   float* __restrict__ accp,
                                                   float* __restrict__ psump) {
    __shared__ __align__(16) union {
        SmemKV kv;                    // 24.6 KB
        float rd[4][QB][DH + 1];      // 34.8 KB
    } sm;
    int ks = blockIdx.x, qc = blockIdx.y, h = blockIdx.z;
    int t = threadIdx.x;
    int wv = t >> 6, lane = t & 63;

    for (int i = t; i < KB * 4; i += 512) {
        int row = i >> 2, c4 = (i & 3) * 4;
        const float* base = qkv + (size_t)(ks * KB + row) * (3 * D) + D + h * DH + c4;
        *(float4*)&sm.kv.k[row][c4] = *(const float4*)base;
        *(float4*)&sm.kv.v[row][c4] = *(const float4*)(base + D);
    }

    float q[2][DH];
#pragma unroll
    for (int j = 0; j < 2; ++j) {
        const float4* qp =
            (const float4*)(qkv + (size_t)(qc * QB + j * 64 + lane) * (3 * D) + h * DH);
#pragma unroll
        for (int e = 0; e < 4; ++e) {
            float4 v = qp[e];
            q[j][e * 4 + 0] = v.x * 0.25f;
            q[j][e * 4 + 1] = v.y * 0.25f;
            q[j][e * 4 + 2] = v.z * 0.25f;
            q[j][e * 4 + 3] = v.w * 0.25f;
        }
    }
    __syncthreads();

    float acc[2][DH];
#pragma unroll
    for (int j = 0; j < 2; ++j)
#pragma unroll
        for (int i = 0; i < DH; ++i) acc[j][i] = 0.f;
    float psum[2] = {0.f, 0.f};

#pragma unroll 2
    for (int jk = 0; jk < KW; ++jk) {
        int r = wv * KW + jk;
        float4 k0 = *(const float4*)&sm.kv.k[r][0];
        float4 k1 = *(const float4*)&sm.kv.k[r][4];
        float4 k2 = *(const float4*)&sm.kv.k[r][8];
        float4 k3 = *(const float4*)&sm.kv.k[r][12];
        float p[2];
#pragma unroll
        for (int j = 0; j < 2; ++j) {
            float s = q[j][0] * k0.x + q[j][1] * k0.y + q[j][2] * k0.z + q[j][3] * k0.w
                    + q[j][4] * k1.x + q[j][5] * k1.y + q[j][6] * k1.z + q[j][7] * k1.w
                    + q[j][8] * k2.x + q[j][9] * k2.y + q[j][10] * k2.z + q[j][11] * k2.w
                    + q[j][12] * k3.x + q[j][13] * k3.y + q[j][14] * k3.z + q[j][15] * k3.w;
            p[j] = __expf(s);
            psum[j] += p[j];
        }
        float4 v0 = *(const float4*)&sm.kv.v[r][0];
        float4 v1 = *(const float4*)&sm.kv.v[r][4];
        float4 v2 = *(const float4*)&sm.kv.v[r][8];
        float4 v3 = *(const float4*)&sm.kv.v[r][12];
#pragma unroll
        for (int j = 0; j < 2; ++j) {
            acc[j][0] += p[j] * v0.x;  acc[j][1] += p[j] * v0.y;
            acc[j][2] += p[j] * v0.z;  acc[j][3] += p[j] * v0.w;
            acc[j][4] += p[j] * v1.x;  acc[j][5] += p[j] * v1.y;
            acc[j][6] += p[j] * v1.z;  acc[j][7] += p[j] * v1.w;
            acc[j][8] += p[j] * v2.x;  acc[j][9] += p[j] * v2.y;
            acc[j][10] += p[j] * v2.z; acc[j][11] += p[j] * v2.w;
            acc[j][12] += p[j] * v3.x; acc[j][13] += p[j] * v3.y;
            acc[j][14] += p[j] * v3.z; acc[j][15] += p[j] * v3.w;
        }
    }

    __syncthreads();
    if (wv < 4) {
#pragma unroll
        for (int j = 0; j < 2; ++j) {
            int qq = j * 64 + lane;
#pragma unroll
            for (int i = 0; i < DH; ++i) sm.rd[wv][qq][i] = acc[j][i];
            sm.rd[wv][qq][DH] = psum[j];
        }
    }
    __syncthreads();
    if (wv >= 4) {
        int w2 = wv - 4;
#pragma unroll
        for (int j = 0; j < 2; ++j) {
            int qq = j * 64 + lane;
#pragma unroll
            for (int i = 0; i < DH; ++i) sm.rd[w2][qq][i] += acc[j][i];
            sm.rd[w2][qq][DH] += psum[j];
        }
    }
    __syncthreads();

    for (int i = t; i < QB * (DH + 1); i += 512) {
        int qq = i / (DH + 1), c = i % (DH + 1);
        float s = sm.rd[0][qq][c] + sm.rd[1][qq][c] + sm.rd[2][qq][c] + sm.rd[3][qq][c];
        int n = qc * QB + qq;
        if (c < DH)
            accp[((size_t)ks * N + n) * D + h * DH + c] = s;
        else
            psump[((size_t)ks * N + n) * H + h] = s;
    }
}

// --- fused: combine partials -> o; out-proj+LN1; ff1; ff2; LN2;
//     optional tail A: qkv for next layer; optional tail B: node+uw. ---
__global__ __launch_bounds__(256) void k_attn_ffn(const float* __restrict__ accp,
                                                  const float* __restrict__ psump,
                                                  const float* __restrict__ ow,
                                                  const float* __restrict__ ob,
                                                  const float* __restrict__ g1,
                                                  const float* __restrict__ be1,
                                                  const float* __restrict__ w1,
                                                  const float* __restrict__ b1,
                                                  const float* __restrict__ w2,
                                                  const float* __restrict__ b2,
                                                  const float* __restrict__ g2,
                                                  const float* __restrict__ be2,
                                                  float* __restrict__ x,
                                                  const float* __restrict__ nw,
                                                  const float* __restrict__ nb,
                                                  float* __restrict__ nqkv,
                                                  int tail,
                                                  const float* __restrict__ nsw,
                                                  const float* __restrict__ nsb,
                                                  const float* __restrict__ e1w,
                                                  const float* __restrict__ e1b,
                                                  float* __restrict__ nodeo,
                                                  float* __restrict__ u,
                                                  float* __restrict__ wbuf) {
    __shared__ __align__(16) float so[4][D];
    __shared__ __align__(16) float sx[4][D];
    __shared__ __align__(16) float sh[4][FFDIM];
    __shared__ float sp[4][4][D];
    int t = threadIdx.x;
    int r = t >> 6, e = t & 63;
    int n = blockIdx.x * 4 + r;

    {
        float a = 0.f, p = 0.f;
#pragma unroll
        for (int pp = 0; pp < NPART; ++pp) {
            a += accp[((size_t)pp * N + n) * D + e];
            p += psump[((size_t)pp * N + n) * H + (e >> 4)];
        }
        so[r][e] = a / p;
    }
    __syncthreads();

    {
        const float4* ir = (const float4*)so[r];
        const float4* wr = (const float4*)(ow + e * D);
        float acc = ob[e];
#pragma unroll
        for (int k = 0; k < D / 4; ++k) acc += dot4(ir[k], wr[k]);
        float y = x[n * D + e] + acc;
        float mu = y;
#pragma unroll
        for (int off = 32; off; off >>= 1) mu += __shfl_xor(mu, off, 64);
        mu *= (1.f / 64.f);
        float diff = y - mu;
        float var = diff * diff;
#pragma unroll
        for (int off = 32; off; off >>= 1) var += __shfl_xor(var, off, 64);
        var *= (1.f / 64.f);
        sx[r][e] = diff * rsqrtf(var + EPS) * g1[e] + be1[e];
    }
    __syncthreads();

    {
        const float4* wr = (const float4*)(w1 + t * D);
        float acc[4];
        float bb = b1[t];
#pragma unroll
        for (int rr = 0; rr < 4; ++rr) acc[rr] = bb;
#pragma unroll
        for (int k = 0; k < D / 4; ++k) {
            float4 wv = wr[k];
#pragma unroll
            for (int rr = 0; rr < 4; ++rr) acc[rr] += dot4(wv, *(const float4*)&sx[rr][k * 4]);
        }
#pragma unroll
        for (int rr = 0; rr < 4; ++rr) sh[rr][t] = fmaxf(acc[rr], 0.f);
    }
    __syncthreads();

    {
        int d = t & 63, c = t >> 6;
        const float4* wr = (const float4*)(w2 + d * FFDIM + c * 64);
        float acc[4] = {0.f, 0.f, 0.f, 0.f};
#pragma unroll
        for (int k = 0; k < 16; ++k) {
            float4 wv = wr[k];
#pragma unroll
            for (int rr = 0; rr < 4; ++rr)
                acc[rr] += dot4(wv, *(const float4*)&sh[rr][c * 64 + k * 4]);
        }
#pragma unroll
        for (int rr = 0; rr < 4; ++rr) sp[rr][c][d] = acc[rr];
    }
    __syncthreads();

    {
        float y = sx[r][e] + b2[e] + sp[r][0][e] + sp[r][1][e] + sp[r][2][e] + sp[r][3][e];
        float mu = y;
#pragma unroll
        for (int off = 32; off; off >>= 1) mu += __shfl_xor(mu, off, 64);
        mu *= (1.f / 64.f);
        float diff = y - mu;
        float var = diff * diff;
#pragma unroll
        for (int off = 32; off; off >>= 1) var += __shfl_xor(var, off, 64);
        var *= (1.f / 64.f);
        float xv = diff * rsqrtf(var + EPS) * g2[e] + be2[e];
        x[n * D + e] = xv;
        sx[r][e] = xv;
    }

    if (nqkv) {
        __syncthreads();
        if (t < 3 * D) {
            const float4* wr = (const float4*)(nw + t * D);
            float bb = nb[t];
            float a0 = bb, a1 = bb, a2 = bb, a3 = bb;
#pragma unroll
            for (int k = 0; k < D / 4; ++k) {
                float4 wv = wr[k];
                a0 += dot4(wv, *(const float4*)&sx[0][k * 4]);
                a1 += dot4(wv, *(const float4*)&sx[1][k * 4]);
                a2 += dot4(wv, *(const float4*)&sx[2][k * 4]);
                a3 += dot4(wv, *(const float4*)&sx[3][k * 4]);
            }
            int n0 = blockIdx.x * 4;
            nqkv[(n0 + 0) * (3 * D) + t] = a0;
            nqkv[(n0 + 1) * (3 * D) + t] = a1;
            nqkv[(n0 + 2) * (3 * D) + t] = a2;
            nqkv[(n0 + 3) * (3 * D) + t] = a3;
        }
    }

    if (!tail) return;
    __syncthreads();

    {
        const float4* xr = (const float4*)sx[r];
        const float4* ar = (const float4*)(e1w + e * 2 * D);
        const float4* br = (const float4*)(e1w + e * 2 * D + D);
        float au = 0.f, aw = 0.f;
#pragma unroll
        for (int k = 0; k < D / 4; ++k) {
            float4 xv = xr[k], av = ar[k], bv = br[k];
            au += dot4(xv, av);
            aw += dot4(xv, bv);
        }
        u[n * D + e] = au + e1b[e];
        wbuf[n * D + e] = aw;
        float p = sx[r][e] * nsw[e];
#pragma unroll
        for (int off = 32; off; off >>= 1) p += __shfl_xor(p, off, 64);
        if (e == 0) nodeo[n] = p + nsb[0];
    }
}

// -------- edge: 64x64 tile/block, 4x4 register blocking, float4 LDS --------
__global__ __launch_bounds__(256) void k_edge(const float* __restrict__ u,
                                              const float* __restrict__ w,
                                              const float* __restrict__ e2w,
                                              const float* __restrict__ e2b,
                                              float* __restrict__ out) {
    __shared__ __align__(16) float su[64][68];
    __shared__ __align__(16) float sw[64][68];
    __shared__ __align__(16) float sv[64];
    int tn = blockIdx.y * 64, tm = blockIdx.x * 64;
    int t = threadIdx.x;
    for (int i = t; i < 64 * 16; i += 256) {
        int r = i >> 4, c4 = (i & 15) * 4;
        *(float4*)&su[r][c4] = *(const float4*)&u[(tn + r) * D + c4];
        *(float4*)&sw[r][c4] = *(const float4*)&w[(tm + r) * D + c4];
    }
    if (t < 64) sv[t] = e2w[t];
    __syncthreads();
    float eb = e2b[0];
    int c0 = t & 15, r0 = t >> 4;

    float acc[4][4];
#pragma unroll
    for (int j = 0; j < 4; ++j)
#pragma unroll
        for (int k = 0; k < 4; ++k) acc[j][k] = 0.f;

#pragma unroll 4
    for (int e0 = 0; e0 < 64; e0 += 4) {
        float4 vv = *(const float4*)&sv[e0];
        float4 a[4], bb[4];
#pragma unroll
        for (int j = 0; j < 4; ++j) a[j] = *(const float4*)&su[r0 + 16 * j][e0];
#pragma unroll
        for (int k = 0; k < 4; ++k) bb[k] = *(const float4*)&sw[c0 + 16 * k][e0];
#pragma unroll
        for (int j = 0; j < 4; ++j)
#pragma unroll
            for (int k = 0; k < 4; ++k) {
                acc[j][k] += fmaxf(a[j].x + bb[k].x, 0.f) * vv.x;
                acc[j][k] += fmaxf(a[j].y + bb[k].y, 0.f) * vv.y;
                acc[j][k] += fmaxf(a[j].z + bb[k].z, 0.f) * vv.z;
                acc[j][k] += fmaxf(a[j].w + bb[k].w, 0.f) * vv.w;
            }
    }
#pragma unroll
    for (int j = 0; j < 4; ++j)
#pragma unroll
        for (int k = 0; k < 4; ++k)
            out[(size_t)(tn + r0 + 16 * j) * N + (tm + c0 + 16 * k)] = acc[j][k] + eb;
}

extern "C" void kernel_launch(void* const* d_in, const int* in_sizes, int n_in,
                              void* d_out, int out_size, void* d_ws, size_t ws_size,
                              hipStream_t stream) {
    const float* node_feats = (const float*)d_in[0];
    const float* proj_w = (const float*)d_in[1];
    const float* proj_b = (const float*)d_in[2];
    const float* in_w = (const float*)d_in[3];
    const float* in_b = (const float*)d_in[4];
    const float* out_w = (const float*)d_in[5];
    const float* out_b = (const float*)d_in[6];
    const float* ff1_w = (const float*)d_in[7];
    const float* ff1_b = (const float*)d_in[8];
    const float* ff2_w = (const float*)d_in[9];
    const float* ff2_b = (const float*)d_in[10];
    const float* ln1_g = (const float*)d_in[11];
    const float* ln1_b = (const float*)d_in[12];
    const float* ln2_g = (const float*)d_in[13];
    const float* ln2_b = (const float*)d_in[14];
    const float* ns_w = (const float*)d_in[15];
    const float* ns_b = (const float*)d_in[16];
    const float* e1_w = (const float*)d_in[17];
    const float* e1_b = (const float*)d_in[18];
    const float* e2_w = (const float*)d_in[19];
    const float* e2_b = (const float*)d_in[20];

    float* out = (float*)d_out;  // [0,1536) node logits, then 1536^2 edge logits

    float* x = (float*)d_ws;               // N*D
    float* qkv = x + N * D;                // N*3D (layer 1 only)
    float* accp = qkv + N * 3 * D;         // NPART*N*D (3.15 MB)
    float* psump = accp + (size_t)NPART * N * D;  // NPART*N*H
    float* u = psump + (size_t)NPART * N * H;     // N*D
    float* wbuf = u + N * D;               // N*D

    dim3 agrid(KS, N / QB, H);

    // layer 0: fused proj+qkv+attention (x written by ks==0,h==0 blocks)
    k_attn0<<<agrid, 512, 0, stream>>>(node_feats, proj_w, proj_b,
                                       in_w, in_b, x, accp, psump);
    // layer 0 epilogue + layer-1 qkv production
    k_attn_ffn<<<N / 4, 256, 0, stream>>>(
        accp, psump, out_w, out_b, ln1_g, ln1_b,
        ff1_w, ff1_b, ff2_w, ff2_b, ln2_g, ln2_b, x,
        in_w + (size_t)3 * D * D, in_b + 3 * D, qkv,
        0, nullptr, nullptr, nullptr, nullptr, nullptr, nullptr, nullptr);
    // layer 1 attention
    k_attn_part<<<agrid, 512, 0, stream>>>(qkv, accp, psump);
    // layer 1 epilogue + node/uw tail
    k_attn_ffn<<<N / 4, 256, 0, stream>>>(
        accp, psump, out_w + (size_t)D * D, out_b + D,
        ln1_g + D, ln1_b + D,
        ff1_w + (size_t)FFDIM * D, ff1_b + FFDIM,
        ff2_w + (size_t)D * FFDIM, ff2_b + D,
        ln2_g + D, ln2_b + D, x,
        nullptr, nullptr, nullptr,
        1, ns_w, ns_b, e1_w, e1_b, out, u, wbuf);
    // edge head
    {
        dim3 grid(N / 64, N / 64);
        k_edge<<<grid, 256, 0, stream>>>(u, wbuf, e2_w, e2_b, out + N);
    }
}

// Round 17
// 102.959 us; speedup vs baseline: 1.2060x; 1.0552x over previous
//
#include <hip/hip_runtime.h>
#include <hip/hip_bf16.h>

#define N 1536
#define F 6
#define D 64
#define H 4
#define DH 16
#define FFDIM 256
#define NL 2
#define EPS 1e-5f
#define KS 8              // key splits across blocks
#define KB (N / KS)       // 192 keys per block
#define NW 8              // waves per attention block (512 threads)
#define KW (KB / NW)      // 24 keys per wave
#define QB 128            // queries per block (2 per lane)
#define NPART KS          // partials per query after in-block combine

typedef _Float16 half2v __attribute__((ext_vector_type(2)));

static __device__ __forceinline__ float dot4(float4 a, float4 b) {
    return a.x * b.x + a.y * b.y + a.z * b.z + a.w * b.w;
}

// ======== layer-0 fused proj+qkv+attention-partial (512 threads) ========
// K stored fp16-packed in LDS (2 b128 reads/row); scores via v_dot2_f32_f16.
union SmA {
    float sinw[48][D];                          // 12.3 KB (phase 2 only)
    struct { half2v kh[KB][8]; float v[KB][DH]; } kv;  // 18.4 KB (phases 3-4)
    float rd[4][QB][DH + 1];                    // 34.8 KB (phase 5, 2-step)
};
__global__ __launch_bounds__(512) void k_attn0(const float* __restrict__ nf,
                                               const float* __restrict__ pw,
                                               const float* __restrict__ pb,
                                               const float* __restrict__ iw,
                                               const float* __restrict__ ib,
                                               float* __restrict__ x,
                                               float* __restrict__ accp,
                                               float* __restrict__ psump) {
    __shared__ __align__(16) SmA sm;
    __shared__ float pwl[D * F];
    __shared__ float pbl[D];
    __shared__ float nfk[KB * F];
    __shared__ float nfq[QB * F];
    __shared__ float eff[48][F];
    __shared__ float beff[48];
    int ks = blockIdx.x, qc = blockIdx.y, h = blockIdx.z;
    int t = threadIdx.x;
    int wv = t >> 6, lane = t & 63;

    // --- phase 1: stage proj weights, nf rows, and this head's in_w rows ---
    for (int i = t; i < D * F; i += 512) pwl[i] = pw[i];
    if (t < D) pbl[t] = pb[t];
    for (int i = t; i < KB * F; i += 512) nfk[i] = nf[ks * KB * F + i];
    for (int i = t; i < QB * F; i += 512) nfq[i] = nf[qc * QB * F + i];
    for (int i = t; i < 48 * D; i += 512) {
        int oo = i >> 6, e = i & 63;
        int o = (oo < 16) ? (h * DH + oo)
              : (oo < 32) ? (D + h * DH + (oo - 16))
                          : (2 * D + h * DH + (oo - 32));
        sm.sinw[oo][e] = iw[o * D + e];
    }
    __syncthreads();

    // --- phase 2: effective (composed) weights ---
    for (int i = t; i < 48 * F; i += 512) {
        int oo = i / F, fx = i % F;
        float a = 0.f;
#pragma unroll 8
        for (int e = 0; e < D; ++e) a += sm.sinw[oo][e] * pwl[e * F + fx];
        eff[oo][fx] = a;
    }
    if (t < 48) {
        int o = (t < 16) ? (h * DH + t)
              : (t < 32) ? (D + h * DH + (t - 16))
                         : (2 * D + h * DH + (t - 32));
        float a = ib[o];
#pragma unroll 8
        for (int e = 0; e < D; ++e) a += sm.sinw[t][e] * pbl[e];
        beff[t] = a;
    }
    __syncthreads();   // sinw dead; kv buffer may now be written

    // --- phase 3: K(fp16)/V(f32) into LDS, q into half2 regs, x write ---
    {
        int i = t & 31, rg = t >> 5;   // rg in [0,16): KB/16 rows each
        int oo = (i < 16) ? (16 + i) : (32 + (i - 16));
        float w0 = eff[oo][0], w1 = eff[oo][1], w2 = eff[oo][2];
        float w3 = eff[oo][3], w4 = eff[oo][4], w5 = eff[oo][5];
        float bo = beff[oo];
        for (int r = rg * (KB / 16); r < (rg + 1) * (KB / 16); ++r) {
            const float* nr = &nfk[r * F];
            float val = bo + nr[0] * w0 + nr[1] * w1 + nr[2] * w2
                           + nr[3] * w3 + nr[4] * w4 + nr[5] * w5;
            if (i < 16) ((_Float16*)&sm.kv.kh[r][0])[i] = (_Float16)val;
            else        sm.kv.v[r][i - 16] = val;
        }
    }
    half2v qh[2][8];
#pragma unroll
    for (int j = 0; j < 2; ++j) {
        const float* nr = &nfq[(j * 64 + lane) * F];
        float n0 = nr[0], n1 = nr[1], n2 = nr[2], n3 = nr[3], n4 = nr[4], n5 = nr[5];
#pragma unroll
        for (int i = 0; i < 8; ++i) {
            float qa = 0.25f * (beff[2 * i] + n0 * eff[2 * i][0] + n1 * eff[2 * i][1]
                     + n2 * eff[2 * i][2] + n3 * eff[2 * i][3]
                     + n4 * eff[2 * i][4] + n5 * eff[2 * i][5]);
            float qb = 0.25f * (beff[2 * i + 1] + n0 * eff[2 * i + 1][0] + n1 * eff[2 * i + 1][1]
                     + n2 * eff[2 * i + 1][2] + n3 * eff[2 * i + 1][3]
                     + n4 * eff[2 * i + 1][4] + n5 * eff[2 * i + 1][5]);
            qh[j][i][0] = (_Float16)qa;
            qh[j][i][1] = (_Float16)qb;
        }
    }
    if (ks == 0 && h == 0) {
        for (int i = t; i < QB * D; i += 512) {
            int row = i >> 6, e = i & 63;
            const float* nr = &nfq[row * F];
            float a = pbl[e];
#pragma unroll
            for (int f = 0; f < F; ++f) a += nr[f] * pwl[e * F + f];
            x[(qc * QB + row) * D + e] = a;
        }
    }
    __syncthreads();

    // --- phase 4: attention partial over this wave's KW keys, 2 q/lane ---
    float acc[2][DH];
#pragma unroll
    for (int j = 0; j < 2; ++j)
#pragma unroll
        for (int i = 0; i < DH; ++i) acc[j][i] = 0.f;
    float psum[2] = {0.f, 0.f};

#pragma unroll 2
    for (int jk = 0; jk < KW; ++jk) {
        int r = wv * KW + jk;
        float4 kA = *(const float4*)&sm.kv.kh[r][0];
        float4 kB = *(const float4*)&sm.kv.kh[r][4];
        const half2v* kap = (const half2v*)&kA;
        const half2v* kbp = (const half2v*)&kB;
        float p[2];
#pragma unroll
        for (int j = 0; j < 2; ++j) {
            float s = 0.f;
#pragma unroll
            for (int d = 0; d < 4; ++d) s = __builtin_amdgcn_fdot2(qh[j][d], kap[d], s, false);
#pragma unroll
            for (int d = 0; d < 4; ++d) s = __builtin_amdgcn_fdot2(qh[j][4 + d], kbp[d], s, false);
            p[j] = __expf(s);
            psum[j] += p[j];
        }
        float4 v0 = *(const float4*)&sm.kv.v[r][0];
        float4 v1 = *(const float4*)&sm.kv.v[r][4];
        float4 v2 = *(const float4*)&sm.kv.v[r][8];
        float4 v3 = *(const float4*)&sm.kv.v[r][12];
#pragma unroll
        for (int j = 0; j < 2; ++j) {
            acc[j][0] += p[j] * v0.x;  acc[j][1] += p[j] * v0.y;
            acc[j][2] += p[j] * v0.z;  acc[j][3] += p[j] * v0.w;
            acc[j][4] += p[j] * v1.x;  acc[j][5] += p[j] * v1.y;
            acc[j][6] += p[j] * v1.z;  acc[j][7] += p[j] * v1.w;
            acc[j][8] += p[j] * v2.x;  acc[j][9] += p[j] * v2.y;
            acc[j][10] += p[j] * v2.z; acc[j][11] += p[j] * v2.w;
            acc[j][12] += p[j] * v3.x; acc[j][13] += p[j] * v3.y;
            acc[j][14] += p[j] * v3.z; acc[j][15] += p[j] * v3.w;
        }
    }

    __syncthreads();  // all kv reads done before rd overlay is written
    if (wv < 4) {
#pragma unroll
        for (int j = 0; j < 2; ++j) {
            int qq = j * 64 + lane;
#pragma unroll
            for (int i = 0; i < DH; ++i) sm.rd[wv][qq][i] = acc[j][i];
            sm.rd[wv][qq][DH] = psum[j];
        }
    }
    __syncthreads();
    if (wv >= 4) {
        int w2 = wv - 4;
#pragma unroll
        for (int j = 0; j < 2; ++j) {
            int qq = j * 64 + lane;
#pragma unroll
            for (int i = 0; i < DH; ++i) sm.rd[w2][qq][i] += acc[j][i];
            sm.rd[w2][qq][DH] += psum[j];
        }
    }
    __syncthreads();

    for (int i = t; i < QB * (DH + 1); i += 512) {
        int qq = i / (DH + 1), c = i % (DH + 1);
        float s = sm.rd[0][qq][c] + sm.rd[1][qq][c] + sm.rd[2][qq][c] + sm.rd[3][qq][c];
        int n = qc * QB + qq;
        if (c < DH)
            accp[((size_t)ks * N + n) * D + h * DH + c] = s;
        else
            psump[((size_t)ks * N + n) * H + h] = s;
    }
}

// ======== layer-1 attention partial (512 threads, fp16 K + fdot2) ========
__global__ __launch_bounds__(512) void k_attn_part(const float* __restrict__ qkv,
                                                   float* __restrict__ accp,
                                                   float* __restrict__ psump) {
    __shared__ __align__(16) union {
        struct { half2v kh[KB][8]; float v[KB][DH]; } kv;  // 18.4 KB
        float rd[4][QB][DH + 1];                           // 34.8 KB
    } sm;
    int ks = blockIdx.x, qc = blockIdx.y, h = blockIdx.z;
    int t = threadIdx.x;
    int wv = t >> 6, lane = t & 63;

    // V staging (f32) + K staging (f32 -> fp16)
    for (int i = t; i < KB * 4; i += 512) {
        int row = i >> 2, c4 = (i & 3) * 4;
        const float* base = qkv + (size_t)(ks * KB + row) * (3 * D) + h * DH + c4;
        *(float4*)&sm.kv.v[row][c4] = *(const float4*)(base + 2 * D);
        float4 kf = *(const float4*)(base + D);
        half2v h0, h1;
        h0[0] = (_Float16)kf.x; h0[1] = (_Float16)kf.y;
        h1[0] = (_Float16)kf.z; h1[1] = (_Float16)kf.w;
        sm.kv.kh[row][(c4 >> 1)] = h0;
        sm.kv.kh[row][(c4 >> 1) + 1] = h1;
    }

    half2v qh[2][8];
#pragma unroll
    for (int j = 0; j < 2; ++j) {
        const float4* qp =
            (const float4*)(qkv + (size_t)(qc * QB + j * 64 + lane) * (3 * D) + h * DH);
#pragma unroll
        for (int e = 0; e < 4; ++e) {
            float4 v = qp[e];
            qh[j][e * 2][0] = (_Float16)(v.x * 0.25f);
            qh[j][e * 2][1] = (_Float16)(v.y * 0.25f);
            qh[j][e * 2 + 1][0] = (_Float16)(v.z * 0.25f);
            qh[j][e * 2 + 1][1] = (_Float16)(v.w * 0.25f);
        }
    }
    __syncthreads();

    float acc[2][DH];
#pragma unroll
    for (int j = 0; j < 2; ++j)
#pragma unroll
        for (int i = 0; i < DH; ++i) acc[j][i] = 0.f;
    float psum[2] = {0.f, 0.f};

#pragma unroll 2
    for (int jk = 0; jk < KW; ++jk) {
        int r = wv * KW + jk;
        float4 kA = *(const float4*)&sm.kv.kh[r][0];
        float4 kB = *(const float4*)&sm.kv.kh[r][4];
        const half2v* kap = (const half2v*)&kA;
        const half2v* kbp = (const half2v*)&kB;
        float p[2];
#pragma unroll
        for (int j = 0; j < 2; ++j) {
            float s = 0.f;
#pragma unroll
            for (int d = 0; d < 4; ++d) s = __builtin_amdgcn_fdot2(qh[j][d], kap[d], s, false);
#pragma unroll
            for (int d = 0; d < 4; ++d) s = __builtin_amdgcn_fdot2(qh[j][4 + d], kbp[d], s, false);
            p[j] = __expf(s);
            psum[j] += p[j];
        }
        float4 v0 = *(const float4*)&sm.kv.v[r][0];
        float4 v1 = *(const float4*)&sm.kv.v[r][4];
        float4 v2 = *(const float4*)&sm.kv.v[r][8];
        float4 v3 = *(const float4*)&sm.kv.v[r][12];
#pragma unroll
        for (int j = 0; j < 2; ++j) {
            acc[j][0] += p[j] * v0.x;  acc[j][1] += p[j] * v0.y;
            acc[j][2] += p[j] * v0.z;  acc[j][3] += p[j] * v0.w;
            acc[j][4] += p[j] * v1.x;  acc[j][5] += p[j] * v1.y;
            acc[j][6] += p[j] * v1.z;  acc[j][7] += p[j] * v1.w;
            acc[j][8] += p[j] * v2.x;  acc[j][9] += p[j] * v2.y;
            acc[j][10] += p[j] * v2.z; acc[j][11] += p[j] * v2.w;
            acc[j][12] += p[j] * v3.x; acc[j][13] += p[j] * v3.y;
            acc[j][14] += p[j] * v3.z; acc[j][15] += p[j] * v3.w;
        }
    }

    __syncthreads();
    if (wv < 4) {
#pragma unroll
        for (int j = 0; j < 2; ++j) {
            int qq = j * 64 + lane;
#pragma unroll
            for (int i = 0; i < DH; ++i) sm.rd[wv][qq][i] = acc[j][i];
            sm.rd[wv][qq][DH] = psum[j];
        }
    }
    __syncthreads();
    if (wv >= 4) {
        int w2 = wv - 4;
#pragma unroll
        for (int j = 0; j < 2; ++j) {
            int qq = j * 64 + lane;
#pragma unroll
            for (int i = 0; i < DH; ++i) sm.rd[w2][qq][i] += acc[j][i];
            sm.rd[w2][qq][DH] += psum[j];
        }
    }
    __syncthreads();

    for (int i = t; i < QB * (DH + 1); i += 512) {
        int qq = i / (DH + 1), c = i % (DH + 1);
        float s = sm.rd[0][qq][c] + sm.rd[1][qq][c] + sm.rd[2][qq][c] + sm.rd[3][qq][c];
        int n = qc * QB + qq;
        if (c < DH)
            accp[((size_t)ks * N + n) * D + h * DH + c] = s;
        else
            psump[((size_t)ks * N + n) * H + h] = s;
    }
}

// --- fused: combine partials -> o; out-proj+LN1; ff1; ff2; LN2;
//     optional tail A: qkv for next layer; optional tail B: node+uw. ---
__global__ __launch_bounds__(256) void k_attn_ffn(const float* __restrict__ accp,
                                                  const float* __restrict__ psump,
                                                  const float* __restrict__ ow,
                                                  const float* __restrict__ ob,
                                                  const float* __restrict__ g1,
                                                  const float* __restrict__ be1,
                                                  const float* __restrict__ w1,
                                                  const float* __restrict__ b1,
                                                  const float* __restrict__ w2,
                                                  const float* __restrict__ b2,
                                                  const float* __restrict__ g2,
                                                  const float* __restrict__ be2,
                                                  float* __restrict__ x,
                                                  const float* __restrict__ nw,
                                                  const float* __restrict__ nb,
                                                  float* __restrict__ nqkv,
                                                  int tail,
                                                  const float* __restrict__ nsw,
                                                  const float* __restrict__ nsb,
                                                  const float* __restrict__ e1w,
                                                  const float* __restrict__ e1b,
                                                  float* __restrict__ nodeo,
                                                  float* __restrict__ u,
                                                  float* __restrict__ wbuf) {
    __shared__ __align__(16) float so[4][D];
    __shared__ __align__(16) float sx[4][D];
    __shared__ __align__(16) float sh[4][FFDIM];
    __shared__ float sp[4][4][D];
    int t = threadIdx.x;
    int r = t >> 6, e = t & 63;
    int n = blockIdx.x * 4 + r;

    {
        float a = 0.f, p = 0.f;
#pragma unroll
        for (int pp = 0; pp < NPART; ++pp) {
            a += accp[((size_t)pp * N + n) * D + e];
            p += psump[((size_t)pp * N + n) * H + (e >> 4)];
        }
        so[r][e] = a / p;
    }
    __syncthreads();

    {
        const float4* ir = (const float4*)so[r];
        const float4* wr = (const float4*)(ow + e * D);
        float acc = ob[e];
#pragma unroll
        for (int k = 0; k < D / 4; ++k) acc += dot4(ir[k], wr[k]);
        float y = x[n * D + e] + acc;
        float mu = y;
#pragma unroll
        for (int off = 32; off; off >>= 1) mu += __shfl_xor(mu, off, 64);
        mu *= (1.f / 64.f);
        float diff = y - mu;
        float var = diff * diff;
#pragma unroll
        for (int off = 32; off; off >>= 1) var += __shfl_xor(var, off, 64);
        var *= (1.f / 64.f);
        sx[r][e] = diff * rsqrtf(var + EPS) * g1[e] + be1[e];
    }
    __syncthreads();

    {
        const float4* wr = (const float4*)(w1 + t * D);
        float acc[4];
        float bb = b1[t];
#pragma unroll
        for (int rr = 0; rr < 4; ++rr) acc[rr] = bb;
#pragma unroll
        for (int k = 0; k < D / 4; ++k) {
            float4 wv = wr[k];
#pragma unroll
            for (int rr = 0; rr < 4; ++rr) acc[rr] += dot4(wv, *(const float4*)&sx[rr][k * 4]);
        }
#pragma unroll
        for (int rr = 0; rr < 4; ++rr) sh[rr][t] = fmaxf(acc[rr], 0.f);
    }
    __syncthreads();

    {
        int d = t & 63, c = t >> 6;
        const float4* wr = (const float4*)(w2 + d * FFDIM + c * 64);
        float acc[4] = {0.f, 0.f, 0.f, 0.f};
#pragma unroll
        for (int k = 0; k < 16; ++k) {
            float4 wv = wr[k];
#pragma unroll
            for (int rr = 0; rr < 4; ++rr)
                acc[rr] += dot4(wv, *(const float4*)&sh[rr][c * 64 + k * 4]);
        }
#pragma unroll
        for (int rr = 0; rr < 4; ++rr) sp[rr][c][d] = acc[rr];
    }
    __syncthreads();

    {
        float y = sx[r][e] + b2[e] + sp[r][0][e] + sp[r][1][e] + sp[r][2][e] + sp[r][3][e];
        float mu = y;
#pragma unroll
        for (int off = 32; off; off >>= 1) mu += __shfl_xor(mu, off, 64);
        mu *= (1.f / 64.f);
        float diff = y - mu;
        float var = diff * diff;
#pragma unroll
        for (int off = 32; off; off >>= 1) var += __shfl_xor(var, off, 64);
        var *= (1.f / 64.f);
        float xv = diff * rsqrtf(var + EPS) * g2[e] + be2[e];
        x[n * D + e] = xv;
        sx[r][e] = xv;
    }

    if (nqkv) {
        __syncthreads();
        if (t < 3 * D) {
            const float4* wr = (const float4*)(nw + t * D);
            float bb = nb[t];
            float a0 = bb, a1 = bb, a2 = bb, a3 = bb;
#pragma unroll
            for (int k = 0; k < D / 4; ++k) {
                float4 wv = wr[k];
                a0 += dot4(wv, *(const float4*)&sx[0][k * 4]);
                a1 += dot4(wv, *(const float4*)&sx[1][k * 4]);
                a2 += dot4(wv, *(const float4*)&sx[2][k * 4]);
                a3 += dot4(wv, *(const float4*)&sx[3][k * 4]);
            }
            int n0 = blockIdx.x * 4;
            nqkv[(n0 + 0) * (3 * D) + t] = a0;
            nqkv[(n0 + 1) * (3 * D) + t] = a1;
            nqkv[(n0 + 2) * (3 * D) + t] = a2;
            nqkv[(n0 + 3) * (3 * D) + t] = a3;
        }
    }

    if (!tail) return;
    __syncthreads();

    {
        const float4* xr = (const float4*)sx[r];
        const float4* ar = (const float4*)(e1w + e * 2 * D);
        const float4* br = (const float4*)(e1w + e * 2 * D + D);
        float au = 0.f, aw = 0.f;
#pragma unroll
        for (int k = 0; k < D / 4; ++k) {
            float4 xv = xr[k], av = ar[k], bv = br[k];
            au += dot4(xv, av);
            aw += dot4(xv, bv);
        }
        u[n * D + e] = au + e1b[e];
        wbuf[n * D + e] = aw;
        float p = sx[r][e] * nsw[e];
#pragma unroll
        for (int off = 32; off; off >>= 1) p += __shfl_xor(p, off, 64);
        if (e == 0) nodeo[n] = p + nsb[0];
    }
}

// -------- edge: 64x64 tile/block, 4x4 register blocking, float4 LDS --------
__global__ __launch_bounds__(256) void k_edge(const float* __restrict__ u,
                                              const float* __restrict__ w,
                                              const float* __restrict__ e2w,
                                              const float* __restrict__ e2b,
                                              float* __restrict__ out) {
    __shared__ __align__(16) float su[64][68];
    __shared__ __align__(16) float sw[64][68];
    __shared__ __align__(16) float sv[64];
    int tn = blockIdx.y * 64, tm = blockIdx.x * 64;
    int t = threadIdx.x;
    for (int i = t; i < 64 * 16; i += 256) {
        int r = i >> 4, c4 = (i & 15) * 4;
        *(float4*)&su[r][c4] = *(const float4*)&u[(tn + r) * D + c4];
        *(float4*)&sw[r][c4] = *(const float4*)&w[(tm + r) * D + c4];
    }
    if (t < 64) sv[t] = e2w[t];
    __syncthreads();
    float eb = e2b[0];
    int c0 = t & 15, r0 = t >> 4;

    float acc[4][4];
#pragma unroll
    for (int j = 0; j < 4; ++j)
#pragma unroll
        for (int k = 0; k < 4; ++k) acc[j][k] = 0.f;

#pragma unroll 4
    for (int e0 = 0; e0 < 64; e0 += 4) {
        float4 vv = *(const float4*)&sv[e0];
        float4 a[4], bb[4];
#pragma unroll
        for (int j = 0; j < 4; ++j) a[j] = *(const float4*)&su[r0 + 16 * j][e0];
#pragma unroll
        for (int k = 0; k < 4; ++k) bb[k] = *(const float4*)&sw[c0 + 16 * k][e0];
#pragma unroll
        for (int j = 0; j < 4; ++j)
#pragma unroll
            for (int k = 0; k < 4; ++k) {
                acc[j][k] += fmaxf(a[j].x + bb[k].x, 0.f) * vv.x;
                acc[j][k] += fmaxf(a[j].y + bb[k].y, 0.f) * vv.y;
                acc[j][k] += fmaxf(a[j].z + bb[k].z, 0.f) * vv.z;
                acc[j][k] += fmaxf(a[j].w + bb[k].w, 0.f) * vv.w;
            }
    }
#pragma unroll
    for (int j = 0; j < 4; ++j)
#pragma unroll
        for (int k = 0; k < 4; ++k)
            out[(size_t)(tn + r0 + 16 * j) * N + (tm + c0 + 16 * k)] = acc[j][k] + eb;
}

extern "C" void kernel_launch(void* const* d_in, const int* in_sizes, int n_in,
                              void* d_out, int out_size, void* d_ws, size_t ws_size,
                              hipStream_t stream) {
    const float* node_feats = (const float*)d_in[0];
    const float* proj_w = (const float*)d_in[1];
    const float* proj_b = (const float*)d_in[2];
    const float* in_w = (const float*)d_in[3];
    const float* in_b = (const float*)d_in[4];
    const float* out_w = (const float*)d_in[5];
    const float* out_b = (const float*)d_in[6];
    const float* ff1_w = (const float*)d_in[7];
    const float* ff1_b = (const float*)d_in[8];
    const float* ff2_w = (const float*)d_in[9];
    const float* ff2_b = (const float*)d_in[10];
    const float* ln1_g = (const float*)d_in[11];
    const float* ln1_b = (const float*)d_in[12];
    const float* ln2_g = (const float*)d_in[13];
    const float* ln2_b = (const float*)d_in[14];
    const float* ns_w = (const float*)d_in[15];
    const float* ns_b = (const float*)d_in[16];
    const float* e1_w = (const float*)d_in[17];
    const float* e1_b = (const float*)d_in[18];
    const float* e2_w = (const float*)d_in[19];
    const float* e2_b = (const float*)d_in[20];

    float* out = (float*)d_out;  // [0,1536) node logits, then 1536^2 edge logits

    float* x = (float*)d_ws;               // N*D
    float* qkv = x + N * D;                // N*3D (layer 1 only)
    float* accp = qkv + N * 3 * D;         // NPART*N*D (3.15 MB)
    float* psump = accp + (size_t)NPART * N * D;  // NPART*N*H
    float* u = psump + (size_t)NPART * N * H;     // N*D
    float* wbuf = u + N * D;               // N*D

    dim3 agrid(KS, N / QB, H);

    // layer 0: fused proj+qkv+attention (x written by ks==0,h==0 blocks)
    k_attn0<<<agrid, 512, 0, stream>>>(node_feats, proj_w, proj_b,
                                       in_w, in_b, x, accp, psump);
    // layer 0 epilogue + layer-1 qkv production
    k_attn_ffn<<<N / 4, 256, 0, stream>>>(
        accp, psump, out_w, out_b, ln1_g, ln1_b,
        ff1_w, ff1_b, ff2_w, ff2_b, ln2_g, ln2_b, x,
        in_w + (size_t)3 * D * D, in_b + 3 * D, qkv,
        0, nullptr, nullptr, nullptr, nullptr, nullptr, nullptr, nullptr);
    // layer 1 attention
    k_attn_part<<<agrid, 512, 0, stream>>>(qkv, accp, psump);
    // layer 1 epilogue + node/uw tail
    k_attn_ffn<<<N / 4, 256, 0, stream>>>(
        accp, psump, out_w + (size_t)D * D, out_b + D,
        ln1_g + D, ln1_b + D,
        ff1_w + (size_t)FFDIM * D, ff1_b + FFDIM,
        ff2_w + (size_t)D * FFDIM, ff2_b + D,
        ln2_g + D, ln2_b + D, x,
        nullptr, nullptr, nullptr,
        1, ns_w, ns_b, e1_w, e1_b, out, u, wbuf);
    // edge head
    {
        dim3 grid(N / 64, N / 64);
        k_edge<<<grid, 256, 0, stream>>>(u, wbuf, e2_w, e2_b, out + N);
    }
}

// Round 19
// 101.549 us; speedup vs baseline: 1.2227x; 1.0139x over previous
//
#include <hip/hip_runtime.h>
#include <hip/hip_bf16.h>

#define N 1536
#define F 6
#define D 64
#define H 4
#define DH 16
#define FFDIM 256
#define NL 2
#define EPS 1e-5f
#define KS 8              // key splits across blocks
#define KB (N / KS)       // 192 keys per block
#define NW 8              // waves per attention block (512 threads)
#define KW (KB / NW)      // 24 keys per wave
#define QB 128            // queries per block (2 per lane)
#define NPART KS          // partials per query after in-block combine

typedef _Float16 half2v __attribute__((ext_vector_type(2)));

static __device__ __forceinline__ float dot4(float4 a, float4 b) {
    return a.x * b.x + a.y * b.y + a.z * b.z + a.w * b.w;
}

// ======== layer-0 fused proj+qkv+attention-partial (512 threads) ========
// K and V stored fp16-packed in LDS (2+2 b128 reads/row); scores via
// v_dot2_f32_f16; PV accumulated in packed f16 (v_pk_fma_f16), psum in f32.
union SmA {
    float sinw[48][D];                          // 12.3 KB (phase 2 only)
    struct { half2v kh[KB][8]; half2v vh[KB][8]; } kv;  // 12.3 KB (phases 3-4)
    float rd[4][QB][DH + 1];                    // 34.8 KB (phase 5, 2-step)
};
__global__ __launch_bounds__(512) void k_attn0(const float* __restrict__ nf,
                                               const float* __restrict__ pw,
                                               const float* __restrict__ pb,
                                               const float* __restrict__ iw,
                                               const float* __restrict__ ib,
                                               float* __restrict__ x,
                                               float* __restrict__ accp,
                                               float* __restrict__ psump) {
    __shared__ __align__(16) SmA sm;
    __shared__ float pwl[D * F];
    __shared__ float pbl[D];
    __shared__ float nfk[KB * F];
    __shared__ float nfq[QB * F];
    __shared__ float eff[48][F];
    __shared__ float beff[48];
    int ks = blockIdx.x, qc = blockIdx.y, h = blockIdx.z;
    int t = threadIdx.x;
    int wv = t >> 6, lane = t & 63;

    // --- phase 1: stage proj weights, nf rows, and this head's in_w rows ---
    for (int i = t; i < D * F; i += 512) pwl[i] = pw[i];
    if (t < D) pbl[t] = pb[t];
    for (int i = t; i < KB * F; i += 512) nfk[i] = nf[ks * KB * F + i];
    for (int i = t; i < QB * F; i += 512) nfq[i] = nf[qc * QB * F + i];
    for (int i = t; i < 48 * D; i += 512) {
        int oo = i >> 6, e = i & 63;
        int o = (oo < 16) ? (h * DH + oo)
              : (oo < 32) ? (D + h * DH + (oo - 16))
                          : (2 * D + h * DH + (oo - 32));
        sm.sinw[oo][e] = iw[o * D + e];
    }
    __syncthreads();

    // --- phase 2: effective (composed) weights ---
    for (int i = t; i < 48 * F; i += 512) {
        int oo = i / F, fx = i % F;
        float a = 0.f;
#pragma unroll 8
        for (int e = 0; e < D; ++e) a += sm.sinw[oo][e] * pwl[e * F + fx];
        eff[oo][fx] = a;
    }
    if (t < 48) {
        int o = (t < 16) ? (h * DH + t)
              : (t < 32) ? (D + h * DH + (t - 16))
                         : (2 * D + h * DH + (t - 32));
        float a = ib[o];
#pragma unroll 8
        for (int e = 0; e < D; ++e) a += sm.sinw[t][e] * pbl[e];
        beff[t] = a;
    }
    __syncthreads();   // sinw dead; kv buffer may now be written

    // --- phase 3: K,V(fp16) into LDS, q into half2 regs, x write ---
    {
        int i = t & 31, rg = t >> 5;   // rg in [0,16): KB/16 rows each
        int oo = (i < 16) ? (16 + i) : (32 + (i - 16));
        float w0 = eff[oo][0], w1 = eff[oo][1], w2 = eff[oo][2];
        float w3 = eff[oo][3], w4 = eff[oo][4], w5 = eff[oo][5];
        float bo = beff[oo];
        for (int r = rg * (KB / 16); r < (rg + 1) * (KB / 16); ++r) {
            const float* nr = &nfk[r * F];
            float val = bo + nr[0] * w0 + nr[1] * w1 + nr[2] * w2
                           + nr[3] * w3 + nr[4] * w4 + nr[5] * w5;
            if (i < 16) ((_Float16*)&sm.kv.kh[r][0])[i] = (_Float16)val;
            else        ((_Float16*)&sm.kv.vh[r][0])[i - 16] = (_Float16)val;
        }
    }
    half2v qh[2][8];
#pragma unroll
    for (int j = 0; j < 2; ++j) {
        const float* nr = &nfq[(j * 64 + lane) * F];
        float n0 = nr[0], n1 = nr[1], n2 = nr[2], n3 = nr[3], n4 = nr[4], n5 = nr[5];
#pragma unroll
        for (int i = 0; i < 8; ++i) {
            float qa = 0.25f * (beff[2 * i] + n0 * eff[2 * i][0] + n1 * eff[2 * i][1]
                     + n2 * eff[2 * i][2] + n3 * eff[2 * i][3]
                     + n4 * eff[2 * i][4] + n5 * eff[2 * i][5]);
            float qb = 0.25f * (beff[2 * i + 1] + n0 * eff[2 * i + 1][0] + n1 * eff[2 * i + 1][1]
                     + n2 * eff[2 * i + 1][2] + n3 * eff[2 * i + 1][3]
                     + n4 * eff[2 * i + 1][4] + n5 * eff[2 * i + 1][5]);
            qh[j][i][0] = (_Float16)qa;
            qh[j][i][1] = (_Float16)qb;
        }
    }
    if (ks == 0 && h == 0) {
        for (int i = t; i < QB * D; i += 512) {
            int row = i >> 6, e = i & 63;
            const float* nr = &nfq[row * F];
            float a = pbl[e];
#pragma unroll
            for (int f = 0; f < F; ++f) a += nr[f] * pwl[e * F + f];
            x[(qc * QB + row) * D + e] = a;
        }
    }
    __syncthreads();

    // --- phase 4: attention partial over this wave's KW keys, 2 q/lane ---
    half2v acc[2][8];
#pragma unroll
    for (int j = 0; j < 2; ++j)
#pragma unroll
        for (int i = 0; i < 8; ++i) acc[j][i] = half2v{(_Float16)0.f, (_Float16)0.f};
    float psum[2] = {0.f, 0.f};

#pragma unroll 2
    for (int jk = 0; jk < KW; ++jk) {
        int r = wv * KW + jk;
        float4 kA = *(const float4*)&sm.kv.kh[r][0];
        float4 kB = *(const float4*)&sm.kv.kh[r][4];
        float4 vA = *(const float4*)&sm.kv.vh[r][0];
        float4 vB = *(const float4*)&sm.kv.vh[r][4];
        const half2v* kap = (const half2v*)&kA;
        const half2v* kbp = (const half2v*)&kB;
        const half2v* vap = (const half2v*)&vA;
        const half2v* vbp = (const half2v*)&vB;
#pragma unroll
        for (int j = 0; j < 2; ++j) {
            float s = 0.f;
#pragma unroll
            for (int d = 0; d < 4; ++d) s = __builtin_amdgcn_fdot2(qh[j][d], kap[d], s, false);
#pragma unroll
            for (int d = 0; d < 4; ++d) s = __builtin_amdgcn_fdot2(qh[j][4 + d], kbp[d], s, false);
            float p = __expf(s);
            psum[j] += p;
            _Float16 ph = (_Float16)p;
            half2v pv = half2v{ph, ph};
#pragma unroll
            for (int d = 0; d < 4; ++d) acc[j][d] += pv * vap[d];
#pragma unroll
            for (int d = 0; d < 4; ++d) acc[j][4 + d] += pv * vbp[d];
        }
    }

    __syncthreads();  // all kv reads done before rd overlay is written
    if (wv < 4) {
#pragma unroll
        for (int j = 0; j < 2; ++j) {
            int qq = j * 64 + lane;
#pragma unroll
            for (int i = 0; i < 8; ++i) {
                sm.rd[wv][qq][2 * i] = (float)acc[j][i][0];
                sm.rd[wv][qq][2 * i + 1] = (float)acc[j][i][1];
            }
            sm.rd[wv][qq][DH] = psum[j];
        }
    }
    __syncthreads();
    if (wv >= 4) {
        int w2 = wv - 4;
#pragma unroll
        for (int j = 0; j < 2; ++j) {
            int qq = j * 64 + lane;
#pragma unroll
            for (int i = 0; i < 8; ++i) {
                sm.rd[w2][qq][2 * i] += (float)acc[j][i][0];
                sm.rd[w2][qq][2 * i + 1] += (float)acc[j][i][1];
            }
            sm.rd[w2][qq][DH] += psum[j];
        }
    }
    __syncthreads();

    for (int i = t; i < QB * (DH + 1); i += 512) {
        int qq = i / (DH + 1), c = i % (DH + 1);
        float s = sm.rd[0][qq][c] + sm.rd[1][qq][c] + sm.rd[2][qq][c] + sm.rd[3][qq][c];
        int n = qc * QB + qq;
        if (c < DH)
            accp[((size_t)ks * N + n) * D + h * DH + c] = s;
        else
            psump[((size_t)ks * N + n) * H + h] = s;
    }
}

// ======== layer-1 attention partial (512 threads, fp16 K/V) ========
__global__ __launch_bounds__(512) void k_attn_part(const float* __restrict__ qkv,
                                                   float* __restrict__ accp,
                                                   float* __restrict__ psump) {
    __shared__ __align__(16) union {
        struct { half2v kh[KB][8]; half2v vh[KB][8]; } kv;  // 12.3 KB
        float rd[4][QB][DH + 1];                            // 34.8 KB
    } sm;
    int ks = blockIdx.x, qc = blockIdx.y, h = blockIdx.z;
    int t = threadIdx.x;
    int wv = t >> 6, lane = t & 63;

    // K,V staging (f32 -> fp16)
    for (int i = t; i < KB * 4; i += 512) {
        int row = i >> 2, c4 = (i & 3) * 4;
        const float* base = qkv + (size_t)(ks * KB + row) * (3 * D) + h * DH + c4;
        float4 kf = *(const float4*)(base + D);
        float4 vf = *(const float4*)(base + 2 * D);
        sm.kv.kh[row][(c4 >> 1)] = half2v{(_Float16)kf.x, (_Float16)kf.y};
        sm.kv.kh[row][(c4 >> 1) + 1] = half2v{(_Float16)kf.z, (_Float16)kf.w};
        sm.kv.vh[row][(c4 >> 1)] = half2v{(_Float16)vf.x, (_Float16)vf.y};
        sm.kv.vh[row][(c4 >> 1) + 1] = half2v{(_Float16)vf.z, (_Float16)vf.w};
    }

    half2v qh[2][8];
#pragma unroll
    for (int j = 0; j < 2; ++j) {
        const float4* qp =
            (const float4*)(qkv + (size_t)(qc * QB + j * 64 + lane) * (3 * D) + h * DH);
#pragma unroll
        for (int e = 0; e < 4; ++e) {
            float4 v = qp[e];
            qh[j][e * 2][0] = (_Float16)(v.x * 0.25f);
            qh[j][e * 2][1] = (_Float16)(v.y * 0.25f);
            qh[j][e * 2 + 1][0] = (_Float16)(v.z * 0.25f);
            qh[j][e * 2 + 1][1] = (_Float16)(v.w * 0.25f);
        }
    }
    __syncthreads();

    half2v acc[2][8];
#pragma unroll
    for (int j = 0; j < 2; ++j)
#pragma unroll
        for (int i = 0; i < 8; ++i) acc[j][i] = half2v{(_Float16)0.f, (_Float16)0.f};
    float psum[2] = {0.f, 0.f};

#pragma unroll 2
    for (int jk = 0; jk < KW; ++jk) {
        int r = wv * KW + jk;
        float4 kA = *(const float4*)&sm.kv.kh[r][0];
        float4 kB = *(const float4*)&sm.kv.kh[r][4];
        float4 vA = *(const float4*)&sm.kv.vh[r][0];
        float4 vB = *(const float4*)&sm.kv.vh[r][4];
        const half2v* kap = (const half2v*)&kA;
        const half2v* kbp = (const half2v*)&kB;
        const half2v* vap = (const half2v*)&vA;
        const half2v* vbp = (const half2v*)&vB;
#pragma unroll
        for (int j = 0; j < 2; ++j) {
            float s = 0.f;
#pragma unroll
            for (int d = 0; d < 4; ++d) s = __builtin_amdgcn_fdot2(qh[j][d], kap[d], s, false);
#pragma unroll
            for (int d = 0; d < 4; ++d) s = __builtin_amdgcn_fdot2(qh[j][4 + d], kbp[d], s, false);
            float p = __expf(s);
            psum[j] += p;
            _Float16 ph = (_Float16)p;
            half2v pv = half2v{ph, ph};
#pragma unroll
            for (int d = 0; d < 4; ++d) acc[j][d] += pv * vap[d];
#pragma unroll
            for (int d = 0; d < 4; ++d) acc[j][4 + d] += pv * vbp[d];
        }
    }

    __syncthreads();
    if (wv < 4) {
#pragma unroll
        for (int j = 0; j < 2; ++j) {
            int qq = j * 64 + lane;
#pragma unroll
            for (int i = 0; i < 8; ++i) {
                sm.rd[wv][qq][2 * i] = (float)acc[j][i][0];
                sm.rd[wv][qq][2 * i + 1] = (float)acc[j][i][1];
            }
            sm.rd[wv][qq][DH] = psum[j];
        }
    }
    __syncthreads();
    if (wv >= 4) {
        int w2 = wv - 4;
#pragma unroll
        for (int j = 0; j < 2; ++j) {
            int qq = j * 64 + lane;
#pragma unroll
            for (int i = 0; i < 8; ++i) {
                sm.rd[w2][qq][2 * i] += (float)acc[j][i][0];
                sm.rd[w2][qq][2 * i + 1] += (float)acc[j][i][1];
            }
            sm.rd[w2][qq][DH] += psum[j];
        }
    }
    __syncthreads();

    for (int i = t; i < QB * (DH + 1); i += 512) {
        int qq = i / (DH + 1), c = i % (DH + 1);
        float s = sm.rd[0][qq][c] + sm.rd[1][qq][c] + sm.rd[2][qq][c] + sm.rd[3][qq][c];
        int n = qc * QB + qq;
        if (c < DH)
            accp[((size_t)ks * N + n) * D + h * DH + c] = s;
        else
            psump[((size_t)ks * N + n) * H + h] = s;
    }
}

// --- fused: combine partials -> o; out-proj+LN1; ff1; ff2; LN2;
//     optional tail A: qkv for next layer; optional tail B: node+uw. ---
__global__ __launch_bounds__(256) void k_attn_ffn(const float* __restrict__ accp,
                                                  const float* __restrict__ psump,
                                                  const float* __restrict__ ow,
                                                  const float* __restrict__ ob,
                                                  const float* __restrict__ g1,
                                                  const float* __restrict__ be1,
                                                  const float* __restrict__ w1,
                                                  const float* __restrict__ b1,
                                                  const float* __restrict__ w2,
                                                  const float* __restrict__ b2,
                                                  const float* __restrict__ g2,
                                                  const float* __restrict__ be2,
                                                  float* __restrict__ x,
                                                  const float* __restrict__ nw,
                                                  const float* __restrict__ nb,
                                                  float* __restrict__ nqkv,
                                                  int tail,
                                                  const float* __restrict__ nsw,
                                                  const float* __restrict__ nsb,
                                                  const float* __restrict__ e1w,
                                                  const float* __restrict__ e1b,
                                                  float* __restrict__ nodeo,
                                                  float* __restrict__ u,
                                                  float* __restrict__ wbuf) {
    __shared__ __align__(16) float so[4][D];
    __shared__ __align__(16) float sx[4][D];
    __shared__ __align__(16) float sh[4][FFDIM];
    __shared__ float sp[4][4][D];
    int t = threadIdx.x;
    int r = t >> 6, e = t & 63;
    int n = blockIdx.x * 4 + r;

    {
        float a = 0.f, p = 0.f;
#pragma unroll
        for (int pp = 0; pp < NPART; ++pp) {
            a += accp[((size_t)pp * N + n) * D + e];
            p += psump[((size_t)pp * N + n) * H + (e >> 4)];
        }
        so[r][e] = a / p;
    }
    __syncthreads();

    {
        const float4* ir = (const float4*)so[r];
        const float4* wr = (const float4*)(ow + e * D);
        float acc = ob[e];
#pragma unroll
        for (int k = 0; k < D / 4; ++k) acc += dot4(ir[k], wr[k]);
        float y = x[n * D + e] + acc;
        float mu = y;
#pragma unroll
        for (int off = 32; off; off >>= 1) mu += __shfl_xor(mu, off, 64);
        mu *= (1.f / 64.f);
        float diff = y - mu;
        float var = diff * diff;
#pragma unroll
        for (int off = 32; off; off >>= 1) var += __shfl_xor(var, off, 64);
        var *= (1.f / 64.f);
        sx[r][e] = diff * rsqrtf(var + EPS) * g1[e] + be1[e];
    }
    __syncthreads();

    {
        const float4* wr = (const float4*)(w1 + t * D);
        float acc[4];
        float bb = b1[t];
#pragma unroll
        for (int rr = 0; rr < 4; ++rr) acc[rr] = bb;
#pragma unroll
        for (int k = 0; k < D / 4; ++k) {
            float4 wv = wr[k];
#pragma unroll
            for (int rr = 0; rr < 4; ++rr) acc[rr] += dot4(wv, *(const float4*)&sx[rr][k * 4]);
        }
#pragma unroll
        for (int rr = 0; rr < 4; ++rr) sh[rr][t] = fmaxf(acc[rr], 0.f);
    }
    __syncthreads();

    {
        int d = t & 63, c = t >> 6;
        const float4* wr = (const float4*)(w2 + d * FFDIM + c * 64);
        float acc[4] = {0.f, 0.f, 0.f, 0.f};
#pragma unroll
        for (int k = 0; k < 16; ++k) {
            float4 wv = wr[k];
#pragma unroll
            for (int rr = 0; rr < 4; ++rr)
                acc[rr] += dot4(wv, *(const float4*)&sh[rr][c * 64 + k * 4]);
        }
#pragma unroll
        for (int rr = 0; rr < 4; ++rr) sp[rr][c][d] = acc[rr];
    }
    __syncthreads();

    {
        float y = sx[r][e] + b2[e] + sp[r][0][e] + sp[r][1][e] + sp[r][2][e] + sp[r][3][e];
        float mu = y;
#pragma unroll
        for (int off = 32; off; off >>= 1) mu += __shfl_xor(mu, off, 64);
        mu *= (1.f / 64.f);
        float diff = y - mu;
        float var = diff * diff;
#pragma unroll
        for (int off = 32; off; off >>= 1) var += __shfl_xor(var, off, 64);
        var *= (1.f / 64.f);
        float xv = diff * rsqrtf(var + EPS) * g2[e] + be2[e];
        x[n * D + e] = xv;
        sx[r][e] = xv;
    }

    if (nqkv) {
        __syncthreads();
        if (t < 3 * D) {
            const float4* wr = (const float4*)(nw + t * D);
            float bb = nb[t];
            float a0 = bb, a1 = bb, a2 = bb, a3 = bb;
#pragma unroll
            for (int k = 0; k < D / 4; ++k) {
                float4 wv = wr[k];
                a0 += dot4(wv, *(const float4*)&sx[0][k * 4]);
                a1 += dot4(wv, *(const float4*)&sx[1][k * 4]);
                a2 += dot4(wv, *(const float4*)&sx[2][k * 4]);
                a3 += dot4(wv, *(const float4*)&sx[3][k * 4]);
            }
            int n0 = blockIdx.x * 4;
            nqkv[(n0 + 0) * (3 * D) + t] = a0;
            nqkv[(n0 + 1) * (3 * D) + t] = a1;
            nqkv[(n0 + 2) * (3 * D) + t] = a2;
            nqkv[(n0 + 3) * (3 * D) + t] = a3;
        }
    }

    if (!tail) return;
    __syncthreads();

    {
        const float4* xr = (const float4*)sx[r];
        const float4* ar = (const float4*)(e1w + e * 2 * D);
        const float4* br = (const float4*)(e1w + e * 2 * D + D);
        float au = 0.f, aw = 0.f;
#pragma unroll
        for (int k = 0; k < D / 4; ++k) {
            float4 xv = xr[k], av = ar[k], bv = br[k];
            au += dot4(xv, av);
            aw += dot4(xv, bv);
        }
        u[n * D + e] = au + e1b[e];
        wbuf[n * D + e] = aw;
        float p = sx[r][e] * nsw[e];
#pragma unroll
        for (int off = 32; off; off >>= 1) p += __shfl_xor(p, off, 64);
        if (e == 0) nodeo[n] = p + nsb[0];
    }
}

// -------- edge: 64x64 tile/block, 4x4 register blocking, float4 LDS --------
__global__ __launch_bounds__(256) void k_edge(const float* __restrict__ u,
                                              const float* __restrict__ w,
                                              const float* __restrict__ e2w,
                                              const float* __restrict__ e2b,
                                              float* __restrict__ out) {
    __shared__ __align__(16) float su[64][68];
    __shared__ __align__(16) float sw[64][68];
    __shared__ __align__(16) float sv[64];
    int tn = blockIdx.y * 64, tm = blockIdx.x * 64;
    int t = threadIdx.x;
    for (int i = t; i < 64 * 16; i += 256) {
        int r = i >> 4, c4 = (i & 15) * 4;
        *(float4*)&su[r][c4] = *(const float4*)&u[(tn + r) * D + c4];
        *(float4*)&sw[r][c4] = *(const float4*)&w[(tm + r) * D + c4];
    }
    if (t < 64) sv[t] = e2w[t];
    __syncthreads();
    float eb = e2b[0];
    int c0 = t & 15, r0 = t >> 4;

    float acc[4][4];
#pragma unroll
    for (int j = 0; j < 4; ++j)
#pragma unroll
        for (int k = 0; k < 4; ++k) acc[j][k] = 0.f;

#pragma unroll 4
    for (int e0 = 0; e0 < 64; e0 += 4) {
        float4 vv = *(const float4*)&sv[e0];
        float4 a[4], bb[4];
#pragma unroll
        for (int j = 0; j < 4; ++j) a[j] = *(const float4*)&su[r0 + 16 * j][e0];
#pragma unroll
        for (int k = 0; k < 4; ++k) bb[k] = *(const float4*)&sw[c0 + 16 * k][e0];
#pragma unroll
        for (int j = 0; j < 4; ++j)
#pragma unroll
            for (int k = 0; k < 4; ++k) {
                acc[j][k] += fmaxf(a[j].x + bb[k].x, 0.f) * vv.x;
                acc[j][k] += fmaxf(a[j].y + bb[k].y, 0.f) * vv.y;
                acc[j][k] += fmaxf(a[j].z + bb[k].z, 0.f) * vv.z;
                acc[j][k] += fmaxf(a[j].w + bb[k].w, 0.f) * vv.w;
            }
    }
#pragma unroll
    for (int j = 0; j < 4; ++j)
#pragma unroll
        for (int k = 0; k < 4; ++k)
            out[(size_t)(tn + r0 + 16 * j) * N + (tm + c0 + 16 * k)] = acc[j][k] + eb;
}

extern "C" void kernel_launch(void* const* d_in, const int* in_sizes, int n_in,
                              void* d_out, int out_size, void* d_ws, size_t ws_size,
                              hipStream_t stream) {
    const float* node_feats = (const float*)d_in[0];
    const float* proj_w = (const float*)d_in[1];
    const float* proj_b = (const float*)d_in[2];
    const float* in_w = (const float*)d_in[3];
    const float* in_b = (const float*)d_in[4];
    const float* out_w = (const float*)d_in[5];
    const float* out_b = (const float*)d_in[6];
    const float* ff1_w = (const float*)d_in[7];
    const float* ff1_b = (const float*)d_in[8];
    const float* ff2_w = (const float*)d_in[9];
    const float* ff2_b = (const float*)d_in[10];
    const float* ln1_g = (const float*)d_in[11];
    const float* ln1_b = (const float*)d_in[12];
    const float* ln2_g = (const float*)d_in[13];
    const float* ln2_b = (const float*)d_in[14];
    const float* ns_w = (const float*)d_in[15];
    const float* ns_b = (const float*)d_in[16];
    const float* e1_w = (const float*)d_in[17];
    const float* e1_b = (const float*)d_in[18];
    const float* e2_w = (const float*)d_in[19];
    const float* e2_b = (const float*)d_in[20];

    float* out = (float*)d_out;  // [0,1536) node logits, then 1536^2 edge logits

    float* x = (float*)d_ws;               // N*D
    float* qkv = x + N * D;                // N*3D (layer 1 only)
    float* accp = qkv + N * 3 * D;         // NPART*N*D (3.15 MB)
    float* psump = accp + (size_t)NPART * N * D;  // NPART*N*H
    float* u = psump + (size_t)NPART * N * H;     // N*D
    float* wbuf = u + N * D;               // N*D

    dim3 agrid(KS, N / QB, H);

    // layer 0: fused proj+qkv+attention (x written by ks==0,h==0 blocks)
    k_attn0<<<agrid, 512, 0, stream>>>(node_feats, proj_w, proj_b,
                                       in_w, in_b, x, accp, psump);
    // layer 0 epilogue + layer-1 qkv production
    k_attn_ffn<<<N / 4, 256, 0, stream>>>(
        accp, psump, out_w, out_b, ln1_g, ln1_b,
        ff1_w, ff1_b, ff2_w, ff2_b, ln2_g, ln2_b, x,
        in_w + (size_t)3 * D * D, in_b + 3 * D, qkv,
        0, nullptr, nullptr, nullptr, nullptr, nullptr, nullptr, nullptr);
    // layer 1 attention
    k_attn_part<<<agrid, 512, 0, stream>>>(qkv, accp, psump);
    // layer 1 epilogue + node/uw tail
    k_attn_ffn<<<N / 4, 256, 0, stream>>>(
        accp, psump, out_w + (size_t)D * D, out_b + D,
        ln1_g + D, ln1_b + D,
        ff1_w + (size_t)FFDIM * D, ff1_b + FFDIM,
        ff2_w + (size_t)D * FFDIM, ff2_b + D,
        ln2_g + D, ln2_b + D, x,
        nullptr, nullptr, nullptr,
        1, ns_w, ns_b, e1_w, e1_b, out, u, wbuf);
    // edge head
    {
        dim3 grid(N / 64, N / 64);
        k_edge<<<grid, 256, 0, stream>>>(u, wbuf, e2_w, e2_b, out + N);
    }
}